// Round 1
// baseline (271.953 us; speedup 1.0000x reference)
//
#include <hip/hip_runtime.h>
#include <math.h>

#define NN 256
#define CZ 128
#define NH 4
#define CH 32
#define HC 128
#define NPIX (NN*NN)
#define L2E   1.4426950408889634f
#define SCALE2 (0.17677669529663687f * 1.4426950408889634f)   // (1/sqrt(32))*log2e

typedef __attribute__((ext_vector_type(8))) short bf16x8;   // 8 bf16 (4 VGPRs)
typedef __attribute__((ext_vector_type(4))) float fx4;      // MFMA accumulator
typedef __attribute__((ext_vector_type(4))) unsigned u32x4;

// --- cheap truncation split: x ~= hi + lo, total err ~2^-16 relative ---
__device__ __forceinline__ unsigned pack_hl(float x) {
    unsigned b  = __builtin_bit_cast(unsigned, x);
    unsigned hb = b & 0xFFFF0000u;
    float r = x - __builtin_bit_cast(float, hb);
    return hb | (__builtin_bit_cast(unsigned, r) >> 16);   // hi in top16, lo in bottom16
}
// load 8 consecutive floats -> hi/lo bf16x8 fragments (trunc split, ~4 VALU/elem)
__device__ __forceinline__ void load_split8(const float* p, bf16x8& h, bf16x8& l) {
    float4 x0 = *(const float4*)p;
    float4 x1 = *(const float4*)(p + 4);
    float xs[8] = {x0.x, x0.y, x0.z, x0.w, x1.x, x1.y, x1.z, x1.w};
    #pragma unroll
    for (int j = 0; j < 8; ++j) {
        unsigned b  = __builtin_bit_cast(unsigned, xs[j]);
        unsigned hb = b & 0xFFFF0000u;
        float r = xs[j] - __builtin_bit_cast(float, hb);
        h[j] = (short)(hb >> 16);
        l[j] = (short)(__builtin_bit_cast(unsigned, r) >> 16);
    }
}
// load 8 packed uint32 (hi|lo) -> hi/lo bf16x8 fragments (~12 VALU total)
__device__ __forceinline__ void deint8(const unsigned* p, bf16x8& h, bf16x8& l) {
    u32x4 e0 = *(const u32x4*)p;
    u32x4 e1 = *(const u32x4*)(p + 4);
    unsigned es[8] = {e0[0], e0[1], e0[2], e0[3], e1[0], e1[1], e1[2], e1[3]};
    unsigned hw[4], lw[4];
    #pragma unroll
    for (int j = 0; j < 4; ++j) {
        unsigned a = es[2 * j], b = es[2 * j + 1];
        hw[j] = (a >> 16) | (b & 0xFFFF0000u);
        lw[j] = (a & 0x0000FFFFu) | (b << 16);
    }
    h = __builtin_bit_cast(bf16x8, u32x4{hw[0], hw[1], hw[2], hw[3]});
    l = __builtin_bit_cast(bf16x8, u32x4{lw[0], lw[1], lw[2], lw[3]});
}

// 2x2x2 quad transpose across lanes: given per-lane words (x = value of tile0,
// y = value of tile1) indexed by quad q = lane>>4, produce
//   x' = [x(q0), x(q2), y(q0), y(q2)],  y' = [x(q1), x(q3), y(q1), y(q3)].
// Implemented with gfx950 dual-dest lane swaps (no LDS, no lgkmcnt).
__device__ __forceinline__ void qtrans(unsigned &x, unsigned &y) {
#if __has_builtin(__builtin_amdgcn_permlane32_swap) && __has_builtin(__builtin_amdgcn_permlane16_swap)
    {
        auto r = __builtin_amdgcn_permlane32_swap(x, y, false, false);
        x = r[0]; y = r[1];
    }
    {
        auto r = __builtin_amdgcn_permlane16_swap(x, y, false, false);
        x = r[0]; y = r[1];
    }
#else
    asm("v_permlane32_swap_b32 %0, %1\n\t"
        "v_permlane16_swap_b32 %0, %1" : "+v"(x), "+v"(y));
#endif
}

// ---------------------------------------------------------------------------
// Kernel 0: pack weights into MFMA B-fragment layout, bf16 hi/lo planes.
// B-frag (16x16x32): lane holds B[k][n], n=lane&15, k=quad*8+j.
// entry index: (kstep*128 + n)*4 + quad. 0=Wq 1=Wk 2=Wv 3=Wg 4=Wo.
// ---------------------------------------------------------------------------
__global__ __launch_bounds__(256) void pack_w_kernel(
    const float* __restrict__ Wq, const float* __restrict__ Wk,
    const float* __restrict__ Wv, const float* __restrict__ Wg,
    const float* __restrict__ Wo, bf16x8* __restrict__ pk)
{
    int id  = blockIdx.x * 256 + threadIdx.x;
    int mid = id >> 11;
    int e   = id & 2047;
    const float* W = (mid == 0) ? Wq : (mid == 1) ? Wk : (mid == 2) ? Wv : (mid == 3) ? Wg : Wo;
    int quad = e & 3, n = (e >> 2) & 127, ks = e >> 9;
    int k0 = ks * 32 + quad * 8;
    bf16x8 h, l;
    #pragma unroll
    for (int j = 0; j < 8; ++j) {
        float x = W[(size_t)(k0 + j) * 128 + n];
        unsigned b  = __builtin_bit_cast(unsigned, x);
        unsigned hb = b & 0xFFFF0000u;
        float r = x - __builtin_bit_cast(float, hb);
        h[j] = (short)(hb >> 16);
        l[j] = (short)(__builtin_bit_cast(unsigned, r) >> 16);
    }
    pk[(size_t)mid * 4096 + e]        = h;
    pk[(size_t)mid * 4096 + 2048 + e] = l;
}

// ---------------------------------------------------------------------------
// Kernel 1: fused LayerNorm + projections via split-bf16 MFMA.
// Outputs (hi|lo packed uint32 unless noted):
//   q_pk [i][h][j][c]    k_pk [i][h][j][c]    v_pk [i][h][c][j]
//   g_ws [pix][h*32+c] (fp32, sigmoid applied)
//   bias_n [h][n1=query][n2=key] (fp32, * log2e) -- natural order, coalesced
// ---------------------------------------------------------------------------
__global__ __launch_bounds__(256) void ln_proj_kernel(
    const float* __restrict__ z, const float* __restrict__ ls, const float* __restrict__ lb,
    const float* __restrict__ Wb, const bf16x8* __restrict__ pk,
    unsigned* __restrict__ q_pk, unsigned* __restrict__ k_pk, unsigned* __restrict__ v_pk,
    float* __restrict__ g_ws, float* __restrict__ bias_n)
{
    __shared__ float zsh[32][132];
    __shared__ float rsum[256], rsq[256];
    __shared__ float pmu[32], prs[32];

    const int t  = threadIdx.x;
    const int p0 = blockIdx.x * 32;
    const int i  = p0 >> 8;
    const int j0 = p0 & 255;

    const float4* z4 = (const float4*)(z + (size_t)p0 * CZ);
    #pragma unroll
    for (int r = 0; r < 4; ++r) {
        int idx4 = t + 256 * r;
        int p = idx4 >> 5, pos = idx4 & 31;
        *(float4*)&zsh[p][pos * 4] = z4[idx4];
    }
    __syncthreads();

    {
        int p = t >> 3, sg = t & 7;
        float s = 0.f, q = 0.f;
        #pragma unroll
        for (int u = 0; u < 16; ++u) { float x = zsh[p][sg * 16 + u]; s += x; q += x * x; }
        rsum[t] = s; rsq[t] = q;
    }
    __syncthreads();
    if (t < 32) {
        float s = 0.f, q = 0.f;
        #pragma unroll
        for (int g = 0; g < 8; ++g) { s += rsum[t * 8 + g]; q += rsq[t * 8 + g]; }
        float mu  = s * (1.0f / 128.0f);
        float var = q * (1.0f / 128.0f) - mu * mu;
        float a   = var + 1e-5f;
        float r   = rsqrtf(a);
        r = r * (1.5f - 0.5f * a * r * r);
        pmu[t] = mu; prs[t] = r;
    }
    __syncthreads();

    #pragma unroll
    for (int r4 = 0; r4 < 4; ++r4) {
        int idx4 = t + 256 * r4;
        int p = idx4 >> 5, pos = idx4 & 31;
        float4 v  = *(float4*)&zsh[p][pos * 4];
        float4 s4 = ((const float4*)ls)[pos];
        float4 b4 = ((const float4*)lb)[pos];
        float mu = pmu[p], rs = prs[p];
        v.x = (v.x - mu) * rs * s4.x + b4.x;
        v.y = (v.y - mu) * rs * s4.y + b4.y;
        v.z = (v.z - mu) * rs * s4.z + b4.z;
        v.w = (v.w - mu) * rs * s4.w + b4.w;
        *(float4*)&zsh[p][pos * 4] = v;
    }
    __syncthreads();

    const int wv = t >> 6, lane = t & 63;
    const int lrow = lane & 15, quad = lane >> 4;
    const bf16x8* ph = pk + (size_t)wv * 4096;
    const bf16x8* pl = ph + 2048;

    fx4 acc[2][8];
    #pragma unroll
    for (int mr = 0; mr < 2; ++mr)
        #pragma unroll
        for (int nc = 0; nc < 8; ++nc)
            acc[mr][nc] = fx4{0.f, 0.f, 0.f, 0.f};

    #pragma unroll
    for (int ks = 0; ks < 4; ++ks) {
        bf16x8 ah[2], al[2];
        #pragma unroll
        for (int mr = 0; mr < 2; ++mr)
            load_split8(&zsh[mr * 16 + lrow][ks * 32 + quad * 8], ah[mr], al[mr]);
        #pragma unroll
        for (int nc = 0; nc < 8; ++nc) {
            int bi = (ks * 128 + nc * 16 + lrow) * 4 + quad;
            bf16x8 bh = ph[bi], bl = pl[bi];
            #pragma unroll
            for (int mr = 0; mr < 2; ++mr) {
                acc[mr][nc] = __builtin_amdgcn_mfma_f32_16x16x32_bf16(ah[mr], bl, acc[mr][nc], 0, 0, 0);
                acc[mr][nc] = __builtin_amdgcn_mfma_f32_16x16x32_bf16(al[mr], bh, acc[mr][nc], 0, 0, 0);
                acc[mr][nc] = __builtin_amdgcn_mfma_f32_16x16x32_bf16(ah[mr], bh, acc[mr][nc], 0, 0, 0);
            }
        }
    }

    // epilogue: C layout col=lane&15, row=quad*4+reg
    #pragma unroll
    for (int mr = 0; mr < 2; ++mr) {
        #pragma unroll
        for (int nc = 0; nc < 8; ++nc) {
            int cg = nc * 16 + lrow;          // channel 0..127
            int h = cg >> 5, cc = cg & 31;
            int jl = mr * 16 + quad * 4;      // local pixel base (4 consecutive)
            fx4 a = acc[mr][nc];
            if (wv == 0) {                    // q packed [j][c]
                unsigned* qp = q_pk + ((size_t)(i * NH + h) * NN + j0 + jl) * CH + cc;
                #pragma unroll
                for (int r = 0; r < 4; ++r) qp[r * CH] = pack_hl(a[r]);
            } else if (wv == 1) {             // k packed [j][c]
                unsigned* kp = k_pk + ((size_t)(i * NH + h) * NN + j0 + jl) * CH + cc;
                #pragma unroll
                for (int r = 0; r < 4; ++r) kp[r * CH] = pack_hl(a[r]);
            } else if (wv == 2) {             // v packed transposed [c][j]
                u32x4 e = {pack_hl(a[0]), pack_hl(a[1]), pack_hl(a[2]), pack_hl(a[3])};
                *(u32x4*)(v_pk + ((size_t)(i * NH + h) * CH + cc) * NN + j0 + jl) = e;
            } else {                          // g (fp32)
                float* gp = g_ws + (size_t)(p0 + jl) * HC + cg;
                #pragma unroll
                for (int r = 0; r < 4; ++r) gp[r * HC] = 1.0f / (1.0f + __expf(-a[r]));
            }
        }
    }

    // bias = zn @ Wb * log2e; natural layout [h][n1=query=i][n2=key=j0+p], coalesced
    if (t < 128) {
        int hh = t >> 5, p = t & 31;
        float b = 0.f;
        for (int d = 0; d < 128; ++d) b = fmaf(zsh[p][d], Wb[d * 4 + hh], b);
        bias_n[(size_t)hh * NPIX + (size_t)i * NN + j0 + p] = b * L2E;
    }
}

// ---------------------------------------------------------------------------
// Kernel 2: MFMA flash attention. Block = one (i,h), 4 waves x 64 queries.
// S^T = K·Q^T (split-bf16), exp2 (no max: |s| small). P^T hi/lo fragments are
// built fully in-register: the C-frag -> B-frag quad redistribution is a
// 2x2x2 lane transpose done with permlane32_swap + permlane16_swap (dual-dest
// swaps, no LDS, no barriers in the whole kernel). O^T = V^T·P^T.
// Q/K/V arrive pre-packed (hi|lo uint32) -> cheap deinterleave.
// Bias in natural [h][query][key] -> one float4 load per tile.
// ---------------------------------------------------------------------------
__global__ __launch_bounds__(256, 4) void attn_kernel(
    const unsigned* __restrict__ q_pk, const unsigned* __restrict__ k_pk,
    const unsigned* __restrict__ v_pk, const float* __restrict__ g_ws,
    const float* __restrict__ bias_n, float* __restrict__ go_ws)
{
    const int t = threadIdx.x;
    const int wv = t >> 6, lane = t & 63;
    const int lrow = lane & 15, quad = lane >> 4;
    const int h = blockIdx.x & 3, i = blockIdx.x >> 2;
    const int qb = wv * 64;

    const unsigned* qs = q_pk + (size_t)(i * NH + h) * NN * CH;
    const unsigned* ks = k_pk + (size_t)(i * NH + h) * NN * CH;
    const unsigned* vs = v_pk + (size_t)(i * NH + h) * CH * NN;
    const float*    bs = bias_n + (size_t)h * NPIX;

    // Q B-frags (hi/lo), 4 query-tiles: lane holds Q^T[k=c=quad*8+j][n=query=lrow]
    bf16x8 qh[4], ql[4];
    #pragma unroll
    for (int nt = 0; nt < 4; ++nt)
        deint8(qs + (size_t)(qb + nt * 16 + lrow) * CH + quad * 8, qh[nt], ql[nt]);

    fx4 oacc[2][4];   // [c-tile][q-tile], O^T C-layout
    #pragma unroll
    for (int ct = 0; ct < 2; ++ct)
        #pragma unroll
        for (int nt = 0; nt < 4; ++nt)
            oacc[ct][nt] = fx4{0.f, 0.f, 0.f, 0.f};
    float lsum[4] = {0.f, 0.f, 0.f, 0.f};

    for (int kb = 0; kb < NN; kb += 32) {
        // K A-frags: lane holds K[m=key=lrow][k=c=quad*8+j]
        bf16x8 kh[2], kl_[2];
        #pragma unroll
        for (int mt = 0; mt < 2; ++mt)
            deint8(ks + (size_t)(kb + mt * 16 + lrow) * CH + quad * 8, kh[mt], kl_[mt]);
        // V A-frags: lane holds V^T[m=c=lrow][k=key=quad*8+j]
        bf16x8 vh[2], vl[2];
        #pragma unroll
        for (int ct = 0; ct < 2; ++ct)
            deint8(vs + (size_t)(ct * 16 + lrow) * NN + kb + quad * 8, vh[ct], vl[ct]);

        #pragma unroll
        for (int nt = 0; nt < 4; ++nt) {
            // per-lane packed score words: w0*=keys quad*4+{0,1}, w1*=keys quad*4+{2,3}
            // index [mt] = 16-key score tile
            unsigned w0h[2], w1h[2], w0l[2], w1l[2];
            #pragma unroll
            for (int mt = 0; mt < 2; ++mt) {
                float4 bv = *(const float4*)(bs + (size_t)(qb + nt * 16 + lrow) * NN
                                                + kb + mt * 16 + quad * 4);

                fx4 sv = fx4{0.f, 0.f, 0.f, 0.f};
                __builtin_amdgcn_s_setprio(1);
                sv = __builtin_amdgcn_mfma_f32_16x16x32_bf16(kh[mt], ql[nt], sv, 0, 0, 0);
                sv = __builtin_amdgcn_mfma_f32_16x16x32_bf16(kl_[mt], qh[nt], sv, 0, 0, 0);
                sv = __builtin_amdgcn_mfma_f32_16x16x32_bf16(kh[mt], qh[nt], sv, 0, 0, 0);
                __builtin_amdgcn_s_setprio(0);

                float e0 = exp2f(fmaf(sv[0], SCALE2, bv.x));
                float e1 = exp2f(fmaf(sv[1], SCALE2, bv.y));
                float e2 = exp2f(fmaf(sv[2], SCALE2, bv.z));
                float e3 = exp2f(fmaf(sv[3], SCALE2, bv.w));
                lsum[nt] += (e0 + e1) + (e2 + e3);

                unsigned b0 = __builtin_bit_cast(unsigned, e0);
                unsigned b1 = __builtin_bit_cast(unsigned, e1);
                unsigned b2 = __builtin_bit_cast(unsigned, e2);
                unsigned b3 = __builtin_bit_cast(unsigned, e3);
                unsigned h01 = (b0 >> 16) | (b1 & 0xFFFF0000u);
                unsigned h23 = (b2 >> 16) | (b3 & 0xFFFF0000u);
                float r0 = e0 - __builtin_bit_cast(float, b0 & 0xFFFF0000u);
                float r1 = e1 - __builtin_bit_cast(float, b1 & 0xFFFF0000u);
                float r2 = e2 - __builtin_bit_cast(float, b2 & 0xFFFF0000u);
                float r3 = e3 - __builtin_bit_cast(float, b3 & 0xFFFF0000u);
                unsigned l01 = (__builtin_bit_cast(unsigned, r0) >> 16)
                             | (__builtin_bit_cast(unsigned, r1) & 0xFFFF0000u);
                unsigned l23 = (__builtin_bit_cast(unsigned, r2) >> 16)
                             | (__builtin_bit_cast(unsigned, r3) & 0xFFFF0000u);
                w0h[mt] = h01; w1h[mt] = h23;
                w0l[mt] = l01; w1l[mt] = l23;
            }

            // C-frag -> B-frag redistribution, fully in-register.
            // After qtrans: w0h[0]=T0 (keys q*8+0,1), w0h[1]=T2 (keys q*8+4,5),
            //               w1h[0]=T1 (keys q*8+2,3), w1h[1]=T3 (keys q*8+6,7).
            qtrans(w0h[0], w0h[1]);
            qtrans(w1h[0], w1h[1]);
            qtrans(w0l[0], w0l[1]);
            qtrans(w1l[0], w1l[1]);
            bf16x8 pbh = __builtin_bit_cast(bf16x8, u32x4{w0h[0], w1h[0], w0h[1], w1h[1]});
            bf16x8 pbl = __builtin_bit_cast(bf16x8, u32x4{w0l[0], w1l[0], w0l[1], w1l[1]});

            __builtin_amdgcn_s_setprio(1);
            #pragma unroll
            for (int ct = 0; ct < 2; ++ct) {
                oacc[ct][nt] = __builtin_amdgcn_mfma_f32_16x16x32_bf16(vh[ct], pbl, oacc[ct][nt], 0, 0, 0);
                oacc[ct][nt] = __builtin_amdgcn_mfma_f32_16x16x32_bf16(vl[ct], pbh, oacc[ct][nt], 0, 0, 0);
                oacc[ct][nt] = __builtin_amdgcn_mfma_f32_16x16x32_bf16(vh[ct], pbh, oacc[ct][nt], 0, 0, 0);
            }
            __builtin_amdgcn_s_setprio(0);
        }
    }

    // epilogue: reduce l over quads, gate, store. O^T: col=query=lrow, row=c=quad*4+r
    #pragma unroll
    for (int nt = 0; nt < 4; ++nt) {
        float s = lsum[nt];
        s += __shfl_xor(s, 16, 64);
        s += __shfl_xor(s, 32, 64);
        float inv = 1.0f / s;
        size_t pix = (size_t)i * NN + qb + nt * 16 + lrow;
        #pragma unroll
        for (int ct = 0; ct < 2; ++ct) {
            const float* gp = g_ws + pix * HC + h * CH + ct * 16 + quad * 4;
            float4 g4 = *(const float4*)gp;
            fx4 o = oacc[ct][nt];
            float4 r;
            r.x = g4.x * o[0] * inv;
            r.y = g4.y * o[1] * inv;
            r.z = g4.z * o[2] * inv;
            r.w = g4.w * o[3] * inv;
            *(float4*)(go_ws + pix * HC + h * CH + ct * 16 + quad * 4) = r;
        }
    }
}

// ---------------------------------------------------------------------------
// Kernel 3: out = go @ Wo via split-bf16 MFMA.
// ---------------------------------------------------------------------------
__global__ __launch_bounds__(256) void outproj_kernel(
    const float* __restrict__ go_ws, const bf16x8* __restrict__ pk, float* __restrict__ out)
{
    __shared__ float gsh[64][132];
    const int t  = threadIdx.x;
    const int p0 = blockIdx.x * 64;

    const float4* g4 = (const float4*)(go_ws + (size_t)p0 * HC);
    #pragma unroll
    for (int r = 0; r < 8; ++r) {
        int idx4 = t + 256 * r;
        int p = idx4 >> 5, pos = idx4 & 31;
        *(float4*)&gsh[p][pos * 4] = g4[idx4];
    }
    __syncthreads();

    const int wv = t >> 6, lane = t & 63;
    const int lrow = lane & 15, quad = lane >> 4;
    const bf16x8* ph = pk + (size_t)4 * 4096;   // Wo
    const bf16x8* pl = ph + 2048;

    fx4 acc[8];
    #pragma unroll
    for (int nc = 0; nc < 8; ++nc) acc[nc] = fx4{0.f, 0.f, 0.f, 0.f};

    #pragma unroll
    for (int ks = 0; ks < 4; ++ks) {
        bf16x8 ah, al;
        load_split8(&gsh[wv * 16 + lrow][ks * 32 + quad * 8], ah, al);
        #pragma unroll
        for (int nc = 0; nc < 8; ++nc) {
            int bi = (ks * 128 + nc * 16 + lrow) * 4 + quad;
            bf16x8 bh = ph[bi], bl = pl[bi];
            acc[nc] = __builtin_amdgcn_mfma_f32_16x16x32_bf16(ah, bl, acc[nc], 0, 0, 0);
            acc[nc] = __builtin_amdgcn_mfma_f32_16x16x32_bf16(al, bh, acc[nc], 0, 0, 0);
            acc[nc] = __builtin_amdgcn_mfma_f32_16x16x32_bf16(ah, bh, acc[nc], 0, 0, 0);
        }
    }

    #pragma unroll
    for (int nc = 0; nc < 8; ++nc) {
        #pragma unroll
        for (int r = 0; r < 4; ++r)
            out[(size_t)(p0 + wv * 16 + quad * 4 + r) * HC + nc * 16 + lrow] = acc[nc][r];
    }
}

// ---------------------------------------------------------------------------
extern "C" void kernel_launch(void* const* d_in, const int* in_sizes, int n_in,
                              void* d_out, int out_size, void* d_ws, size_t ws_size,
                              hipStream_t stream)
{
    const float* z  = (const float*)d_in[0];
    const float* ls = (const float*)d_in[1];
    const float* lb = (const float*)d_in[2];
    const float* Wq = (const float*)d_in[3];
    const float* Wk = (const float*)d_in[4];
    const float* Wv = (const float*)d_in[5];
    const float* Wb = (const float*)d_in[6];
    const float* Wg = (const float*)d_in[7];
    const float* Wo = (const float*)d_in[8];

    float* ws = (float*)d_ws;
    const size_t BIG = (size_t)NPIX * HC;
    unsigned* q_pk  = (unsigned*)ws;
    unsigned* k_pk  = (unsigned*)(ws + BIG);
    unsigned* v_pk  = (unsigned*)(ws + 2 * BIG);
    float* g_ws     = ws + 3 * BIG;
    float* go_ws    = ws + 4 * BIG;
    float* bias_n   = ws + 5 * BIG;                            // NH*NPIX floats
    bf16x8* pk      = (bf16x8*)(bias_n + (size_t)NH * NPIX);   // 5 x 64 KB packs

    pack_w_kernel<<<40, 256, 0, stream>>>(Wq, Wk, Wv, Wg, Wo, pk);
    ln_proj_kernel<<<NPIX / 32, 256, 0, stream>>>(z, ls, lb, Wb, pk,
                                                  q_pk, k_pk, v_pk, g_ws, bias_n);
    attn_kernel<<<NN * NH, 256, 0, stream>>>(q_pk, k_pk, v_pk, g_ws, bias_n, go_ws);
    outproj_kernel<<<NPIX / 64, 256, 0, stream>>>(go_ws, pk, (float*)d_out);
}

// Round 2
// 254.134 us; speedup vs baseline: 1.0701x; 1.0701x over previous
//
#include <hip/hip_runtime.h>
#include <math.h>

#define NN 256
#define CZ 128
#define NH 4
#define CH 32
#define HC 128
#define NPIX (NN*NN)
#define L2E   1.4426950408889634f
#define SCALE2 (0.17677669529663687f * 1.4426950408889634f)   // (1/sqrt(32))*log2e

typedef __attribute__((ext_vector_type(8))) short bf16x8;   // 8 bf16 (4 VGPRs)
typedef __attribute__((ext_vector_type(4))) float fx4;      // MFMA accumulator
typedef __attribute__((ext_vector_type(4))) unsigned u32x4;

// --- cheap truncation split: x ~= hi + lo, total err ~2^-16 relative ---
__device__ __forceinline__ unsigned pack_hl(float x) {
    unsigned b  = __builtin_bit_cast(unsigned, x);
    unsigned hb = b & 0xFFFF0000u;
    float r = x - __builtin_bit_cast(float, hb);
    return hb | (__builtin_bit_cast(unsigned, r) >> 16);   // hi in top16, lo in bottom16
}
// load 8 consecutive floats -> hi/lo bf16x8 fragments (trunc split, ~4 VALU/elem)
__device__ __forceinline__ void load_split8(const float* p, bf16x8& h, bf16x8& l) {
    float4 x0 = *(const float4*)p;
    float4 x1 = *(const float4*)(p + 4);
    float xs[8] = {x0.x, x0.y, x0.z, x0.w, x1.x, x1.y, x1.z, x1.w};
    #pragma unroll
    for (int j = 0; j < 8; ++j) {
        unsigned b  = __builtin_bit_cast(unsigned, xs[j]);
        unsigned hb = b & 0xFFFF0000u;
        float r = xs[j] - __builtin_bit_cast(float, hb);
        h[j] = (short)(hb >> 16);
        l[j] = (short)(__builtin_bit_cast(unsigned, r) >> 16);
    }
}
// load 8 packed uint32 (hi|lo) -> hi/lo bf16x8 fragments (~12 VALU total)
__device__ __forceinline__ void deint8(const unsigned* p, bf16x8& h, bf16x8& l) {
    u32x4 e0 = *(const u32x4*)p;
    u32x4 e1 = *(const u32x4*)(p + 4);
    unsigned es[8] = {e0[0], e0[1], e0[2], e0[3], e1[0], e1[1], e1[2], e1[3]};
    unsigned hw[4], lw[4];
    #pragma unroll
    for (int j = 0; j < 4; ++j) {
        unsigned a = es[2 * j], b = es[2 * j + 1];
        hw[j] = (a >> 16) | (b & 0xFFFF0000u);
        lw[j] = (a & 0x0000FFFFu) | (b << 16);
    }
    h = __builtin_bit_cast(bf16x8, u32x4{hw[0], hw[1], hw[2], hw[3]});
    l = __builtin_bit_cast(bf16x8, u32x4{lw[0], lw[1], lw[2], lw[3]});
}

// 2x2x2 quad transpose across lanes: given per-lane words (x = value of tile0,
// y = value of tile1) indexed by quad q = lane>>4, produce
//   x' = [x(q0), x(q2), y(q0), y(q2)],  y' = [x(q1), x(q3), y(q1), y(q3)].
// Implemented with gfx950 dual-dest lane swaps (no LDS, no lgkmcnt).
__device__ __forceinline__ void qtrans(unsigned &x, unsigned &y) {
#if __has_builtin(__builtin_amdgcn_permlane32_swap) && __has_builtin(__builtin_amdgcn_permlane16_swap)
    {
        auto r = __builtin_amdgcn_permlane32_swap(x, y, false, false);
        x = r[0]; y = r[1];
    }
    {
        auto r = __builtin_amdgcn_permlane16_swap(x, y, false, false);
        x = r[0]; y = r[1];
    }
#else
    asm("v_permlane32_swap_b32 %0, %1\n\t"
        "v_permlane16_swap_b32 %0, %1" : "+v"(x), "+v"(y));
#endif
}

// ---------------------------------------------------------------------------
// Kernel 0: pack weights into MFMA B-fragment layout, bf16 hi/lo planes.
// B-frag (16x16x32): lane holds B[k][n], n=lane&15, k=quad*8+j.
// entry index: (kstep*128 + n)*4 + quad. 0=Wq 1=Wk 2=Wv 3=Wg 4=Wo.
// ---------------------------------------------------------------------------
__global__ __launch_bounds__(256) void pack_w_kernel(
    const float* __restrict__ Wq, const float* __restrict__ Wk,
    const float* __restrict__ Wv, const float* __restrict__ Wg,
    const float* __restrict__ Wo, bf16x8* __restrict__ pk)
{
    int id  = blockIdx.x * 256 + threadIdx.x;
    int mid = id >> 11;
    int e   = id & 2047;
    const float* W = (mid == 0) ? Wq : (mid == 1) ? Wk : (mid == 2) ? Wv : (mid == 3) ? Wg : Wo;
    int quad = e & 3, n = (e >> 2) & 127, ks = e >> 9;
    int k0 = ks * 32 + quad * 8;
    bf16x8 h, l;
    #pragma unroll
    for (int j = 0; j < 8; ++j) {
        float x = W[(size_t)(k0 + j) * 128 + n];
        unsigned b  = __builtin_bit_cast(unsigned, x);
        unsigned hb = b & 0xFFFF0000u;
        float r = x - __builtin_bit_cast(float, hb);
        h[j] = (short)(hb >> 16);
        l[j] = (short)(__builtin_bit_cast(unsigned, r) >> 16);
    }
    pk[(size_t)mid * 4096 + e]        = h;
    pk[(size_t)mid * 4096 + 2048 + e] = l;
}

// ---------------------------------------------------------------------------
// Kernel 1: fused LayerNorm + projections via split-bf16 MFMA.
// Outputs (hi|lo packed uint32 unless noted):
//   q_pk [i][h][j][c]    k_pk [i][h][j][c]    v_pk [i][h][c][j]
//   g_ws [pix][h*32+c] (fp32, sigmoid applied)
//   bias_n [h][n1=query][n2=key] (fp32, * log2e) -- natural order, coalesced
// ---------------------------------------------------------------------------
__global__ __launch_bounds__(256) void ln_proj_kernel(
    const float* __restrict__ z, const float* __restrict__ ls, const float* __restrict__ lb,
    const float* __restrict__ Wb, const bf16x8* __restrict__ pk,
    unsigned* __restrict__ q_pk, unsigned* __restrict__ k_pk, unsigned* __restrict__ v_pk,
    float* __restrict__ g_ws, float* __restrict__ bias_n)
{
    __shared__ float zsh[32][132];
    __shared__ float rsum[256], rsq[256];
    __shared__ float pmu[32], prs[32];

    const int t  = threadIdx.x;
    const int p0 = blockIdx.x * 32;
    const int i  = p0 >> 8;
    const int j0 = p0 & 255;

    const float4* z4 = (const float4*)(z + (size_t)p0 * CZ);
    #pragma unroll
    for (int r = 0; r < 4; ++r) {
        int idx4 = t + 256 * r;
        int p = idx4 >> 5, pos = idx4 & 31;
        *(float4*)&zsh[p][pos * 4] = z4[idx4];
    }
    __syncthreads();

    {
        int p = t >> 3, sg = t & 7;
        float s = 0.f, q = 0.f;
        #pragma unroll
        for (int u = 0; u < 16; ++u) { float x = zsh[p][sg * 16 + u]; s += x; q += x * x; }
        rsum[t] = s; rsq[t] = q;
    }
    __syncthreads();
    if (t < 32) {
        float s = 0.f, q = 0.f;
        #pragma unroll
        for (int g = 0; g < 8; ++g) { s += rsum[t * 8 + g]; q += rsq[t * 8 + g]; }
        float mu  = s * (1.0f / 128.0f);
        float var = q * (1.0f / 128.0f) - mu * mu;
        float a   = var + 1e-5f;
        float r   = rsqrtf(a);
        r = r * (1.5f - 0.5f * a * r * r);
        pmu[t] = mu; prs[t] = r;
    }
    __syncthreads();

    #pragma unroll
    for (int r4 = 0; r4 < 4; ++r4) {
        int idx4 = t + 256 * r4;
        int p = idx4 >> 5, pos = idx4 & 31;
        float4 v  = *(float4*)&zsh[p][pos * 4];
        float4 s4 = ((const float4*)ls)[pos];
        float4 b4 = ((const float4*)lb)[pos];
        float mu = pmu[p], rs = prs[p];
        v.x = (v.x - mu) * rs * s4.x + b4.x;
        v.y = (v.y - mu) * rs * s4.y + b4.y;
        v.z = (v.z - mu) * rs * s4.z + b4.z;
        v.w = (v.w - mu) * rs * s4.w + b4.w;
        *(float4*)&zsh[p][pos * 4] = v;
    }
    __syncthreads();

    const int wv = t >> 6, lane = t & 63;
    const int lrow = lane & 15, quad = lane >> 4;
    const bf16x8* ph = pk + (size_t)wv * 4096;
    const bf16x8* pl = ph + 2048;

    fx4 acc[2][8];
    #pragma unroll
    for (int mr = 0; mr < 2; ++mr)
        #pragma unroll
        for (int nc = 0; nc < 8; ++nc)
            acc[mr][nc] = fx4{0.f, 0.f, 0.f, 0.f};

    #pragma unroll
    for (int ks = 0; ks < 4; ++ks) {
        bf16x8 ah[2], al[2];
        #pragma unroll
        for (int mr = 0; mr < 2; ++mr)
            load_split8(&zsh[mr * 16 + lrow][ks * 32 + quad * 8], ah[mr], al[mr]);
        #pragma unroll
        for (int nc = 0; nc < 8; ++nc) {
            int bi = (ks * 128 + nc * 16 + lrow) * 4 + quad;
            bf16x8 bh = ph[bi], bl = pl[bi];
            #pragma unroll
            for (int mr = 0; mr < 2; ++mr) {
                acc[mr][nc] = __builtin_amdgcn_mfma_f32_16x16x32_bf16(ah[mr], bl, acc[mr][nc], 0, 0, 0);
                acc[mr][nc] = __builtin_amdgcn_mfma_f32_16x16x32_bf16(al[mr], bh, acc[mr][nc], 0, 0, 0);
                acc[mr][nc] = __builtin_amdgcn_mfma_f32_16x16x32_bf16(ah[mr], bh, acc[mr][nc], 0, 0, 0);
            }
        }
    }

    // epilogue: C layout col=lane&15, row=quad*4+reg
    #pragma unroll
    for (int mr = 0; mr < 2; ++mr) {
        #pragma unroll
        for (int nc = 0; nc < 8; ++nc) {
            int cg = nc * 16 + lrow;          // channel 0..127
            int h = cg >> 5, cc = cg & 31;
            int jl = mr * 16 + quad * 4;      // local pixel base (4 consecutive)
            fx4 a = acc[mr][nc];
            if (wv == 0) {                    // q packed [j][c]
                unsigned* qp = q_pk + ((size_t)(i * NH + h) * NN + j0 + jl) * CH + cc;
                #pragma unroll
                for (int r = 0; r < 4; ++r) qp[r * CH] = pack_hl(a[r]);
            } else if (wv == 1) {             // k packed [j][c]
                unsigned* kp = k_pk + ((size_t)(i * NH + h) * NN + j0 + jl) * CH + cc;
                #pragma unroll
                for (int r = 0; r < 4; ++r) kp[r * CH] = pack_hl(a[r]);
            } else if (wv == 2) {             // v packed transposed [c][j]
                u32x4 e = {pack_hl(a[0]), pack_hl(a[1]), pack_hl(a[2]), pack_hl(a[3])};
                *(u32x4*)(v_pk + ((size_t)(i * NH + h) * CH + cc) * NN + j0 + jl) = e;
            } else {                          // g (fp32)
                float* gp = g_ws + (size_t)(p0 + jl) * HC + cg;
                #pragma unroll
                for (int r = 0; r < 4; ++r) gp[r * HC] = 1.0f / (1.0f + __expf(-a[r]));
            }
        }
    }

    // bias = zn @ Wb * log2e; natural layout [h][n1=query=i][n2=key=j0+p], coalesced
    if (t < 128) {
        int hh = t >> 5, p = t & 31;
        float b = 0.f;
        for (int d = 0; d < 128; ++d) b = fmaf(zsh[p][d], Wb[d * 4 + hh], b);
        bias_n[(size_t)hh * NPIX + (size_t)i * NN + j0 + p] = b * L2E;
    }
}

// ---------------------------------------------------------------------------
// Kernel 2: MFMA flash attention. Block = one (i,h), 4 waves x 64 queries.
// S^T = K·Q^T (split-bf16), exp2 (no max: |s| small). P^T hi/lo fragments are
// built fully in-register: the C-frag -> B-frag quad redistribution is a
// 2x2x2 lane transpose done with permlane32_swap + permlane16_swap (dual-dest
// swaps, no LDS, no barriers in the whole kernel). O^T = V^T·P^T.
// Q/K/V arrive pre-packed (hi|lo uint32) -> cheap deinterleave.
// Bias in natural [h][query][key] -> one float4 load per tile.
// NOTE: plain __launch_bounds__(256) -- the (256,4) variant forced a 64-VGPR
// cap and spilled ~37 MB/dispatch to scratch (round-1 regression).
// ---------------------------------------------------------------------------
__global__ __launch_bounds__(256) void attn_kernel(
    const unsigned* __restrict__ q_pk, const unsigned* __restrict__ k_pk,
    const unsigned* __restrict__ v_pk, const float* __restrict__ g_ws,
    const float* __restrict__ bias_n, float* __restrict__ go_ws)
{
    const int t = threadIdx.x;
    const int wv = t >> 6, lane = t & 63;
    const int lrow = lane & 15, quad = lane >> 4;
    const int h = blockIdx.x & 3, i = blockIdx.x >> 2;
    const int qb = wv * 64;

    const unsigned* qs = q_pk + (size_t)(i * NH + h) * NN * CH;
    const unsigned* ks = k_pk + (size_t)(i * NH + h) * NN * CH;
    const unsigned* vs = v_pk + (size_t)(i * NH + h) * CH * NN;
    const float*    bs = bias_n + (size_t)h * NPIX;

    // Q B-frags (hi/lo), 4 query-tiles: lane holds Q^T[k=c=quad*8+j][n=query=lrow]
    bf16x8 qh[4], ql[4];
    #pragma unroll
    for (int nt = 0; nt < 4; ++nt)
        deint8(qs + (size_t)(qb + nt * 16 + lrow) * CH + quad * 8, qh[nt], ql[nt]);

    fx4 oacc[2][4];   // [c-tile][q-tile], O^T C-layout
    #pragma unroll
    for (int ct = 0; ct < 2; ++ct)
        #pragma unroll
        for (int nt = 0; nt < 4; ++nt)
            oacc[ct][nt] = fx4{0.f, 0.f, 0.f, 0.f};
    float lsum[4] = {0.f, 0.f, 0.f, 0.f};

    for (int kb = 0; kb < NN; kb += 32) {
        // K A-frags: lane holds K[m=key=lrow][k=c=quad*8+j]
        bf16x8 kh[2], kl_[2];
        #pragma unroll
        for (int mt = 0; mt < 2; ++mt)
            deint8(ks + (size_t)(kb + mt * 16 + lrow) * CH + quad * 8, kh[mt], kl_[mt]);
        // V A-frags: lane holds V^T[m=c=lrow][k=key=quad*8+j]
        bf16x8 vh[2], vl[2];
        #pragma unroll
        for (int ct = 0; ct < 2; ++ct)
            deint8(vs + (size_t)(ct * 16 + lrow) * NN + kb + quad * 8, vh[ct], vl[ct]);

        #pragma unroll
        for (int nt = 0; nt < 4; ++nt) {
            // per-lane packed score words: w0*=keys quad*4+{0,1}, w1*=keys quad*4+{2,3}
            // index [mt] = 16-key score tile
            unsigned w0h[2], w1h[2], w0l[2], w1l[2];
            #pragma unroll
            for (int mt = 0; mt < 2; ++mt) {
                float4 bv = *(const float4*)(bs + (size_t)(qb + nt * 16 + lrow) * NN
                                                + kb + mt * 16 + quad * 4);

                fx4 sv = fx4{0.f, 0.f, 0.f, 0.f};
                __builtin_amdgcn_s_setprio(1);
                sv = __builtin_amdgcn_mfma_f32_16x16x32_bf16(kh[mt], ql[nt], sv, 0, 0, 0);
                sv = __builtin_amdgcn_mfma_f32_16x16x32_bf16(kl_[mt], qh[nt], sv, 0, 0, 0);
                sv = __builtin_amdgcn_mfma_f32_16x16x32_bf16(kh[mt], qh[nt], sv, 0, 0, 0);
                __builtin_amdgcn_s_setprio(0);

                float e0 = exp2f(fmaf(sv[0], SCALE2, bv.x));
                float e1 = exp2f(fmaf(sv[1], SCALE2, bv.y));
                float e2 = exp2f(fmaf(sv[2], SCALE2, bv.z));
                float e3 = exp2f(fmaf(sv[3], SCALE2, bv.w));
                lsum[nt] += (e0 + e1) + (e2 + e3);

                unsigned b0 = __builtin_bit_cast(unsigned, e0);
                unsigned b1 = __builtin_bit_cast(unsigned, e1);
                unsigned b2 = __builtin_bit_cast(unsigned, e2);
                unsigned b3 = __builtin_bit_cast(unsigned, e3);
                unsigned h01 = (b0 >> 16) | (b1 & 0xFFFF0000u);
                unsigned h23 = (b2 >> 16) | (b3 & 0xFFFF0000u);
                float r0 = e0 - __builtin_bit_cast(float, b0 & 0xFFFF0000u);
                float r1 = e1 - __builtin_bit_cast(float, b1 & 0xFFFF0000u);
                float r2 = e2 - __builtin_bit_cast(float, b2 & 0xFFFF0000u);
                float r3 = e3 - __builtin_bit_cast(float, b3 & 0xFFFF0000u);
                unsigned l01 = (__builtin_bit_cast(unsigned, r0) >> 16)
                             | (__builtin_bit_cast(unsigned, r1) & 0xFFFF0000u);
                unsigned l23 = (__builtin_bit_cast(unsigned, r2) >> 16)
                             | (__builtin_bit_cast(unsigned, r3) & 0xFFFF0000u);
                w0h[mt] = h01; w1h[mt] = h23;
                w0l[mt] = l01; w1l[mt] = l23;
            }

            // C-frag -> B-frag redistribution, fully in-register.
            // After qtrans: w0h[0]=T0 (keys q*8+0,1), w0h[1]=T2 (keys q*8+4,5),
            //               w1h[0]=T1 (keys q*8+2,3), w1h[1]=T3 (keys q*8+6,7).
            qtrans(w0h[0], w0h[1]);
            qtrans(w1h[0], w1h[1]);
            qtrans(w0l[0], w0l[1]);
            qtrans(w1l[0], w1l[1]);
            bf16x8 pbh = __builtin_bit_cast(bf16x8, u32x4{w0h[0], w1h[0], w0h[1], w1h[1]});
            bf16x8 pbl = __builtin_bit_cast(bf16x8, u32x4{w0l[0], w1l[0], w0l[1], w1l[1]});

            __builtin_amdgcn_s_setprio(1);
            #pragma unroll
            for (int ct = 0; ct < 2; ++ct) {
                oacc[ct][nt] = __builtin_amdgcn_mfma_f32_16x16x32_bf16(vh[ct], pbl, oacc[ct][nt], 0, 0, 0);
                oacc[ct][nt] = __builtin_amdgcn_mfma_f32_16x16x32_bf16(vl[ct], pbh, oacc[ct][nt], 0, 0, 0);
                oacc[ct][nt] = __builtin_amdgcn_mfma_f32_16x16x32_bf16(vh[ct], pbh, oacc[ct][nt], 0, 0, 0);
            }
            __builtin_amdgcn_s_setprio(0);
        }
    }

    // epilogue: reduce l over quads, gate, store. O^T: col=query=lrow, row=c=quad*4+r
    #pragma unroll
    for (int nt = 0; nt < 4; ++nt) {
        float s = lsum[nt];
        s += __shfl_xor(s, 16, 64);
        s += __shfl_xor(s, 32, 64);
        float inv = 1.0f / s;
        size_t pix = (size_t)i * NN + qb + nt * 16 + lrow;
        #pragma unroll
        for (int ct = 0; ct < 2; ++ct) {
            const float* gp = g_ws + pix * HC + h * CH + ct * 16 + quad * 4;
            float4 g4 = *(const float4*)gp;
            fx4 o = oacc[ct][nt];
            float4 r;
            r.x = g4.x * o[0] * inv;
            r.y = g4.y * o[1] * inv;
            r.z = g4.z * o[2] * inv;
            r.w = g4.w * o[3] * inv;
            *(float4*)(go_ws + pix * HC + h * CH + ct * 16 + quad * 4) = r;
        }
    }
}

// ---------------------------------------------------------------------------
// Kernel 3: out = go @ Wo via split-bf16 MFMA.
// ---------------------------------------------------------------------------
__global__ __launch_bounds__(256) void outproj_kernel(
    const float* __restrict__ go_ws, const bf16x8* __restrict__ pk, float* __restrict__ out)
{
    __shared__ float gsh[64][132];
    const int t  = threadIdx.x;
    const int p0 = blockIdx.x * 64;

    const float4* g4 = (const float4*)(go_ws + (size_t)p0 * HC);
    #pragma unroll
    for (int r = 0; r < 8; ++r) {
        int idx4 = t + 256 * r;
        int p = idx4 >> 5, pos = idx4 & 31;
        *(float4*)&gsh[p][pos * 4] = g4[idx4];
    }
    __syncthreads();

    const int wv = t >> 6, lane = t & 63;
    const int lrow = lane & 15, quad = lane >> 4;
    const bf16x8* ph = pk + (size_t)4 * 4096;   // Wo
    const bf16x8* pl = ph + 2048;

    fx4 acc[8];
    #pragma unroll
    for (int nc = 0; nc < 8; ++nc) acc[nc] = fx4{0.f, 0.f, 0.f, 0.f};

    #pragma unroll
    for (int ks = 0; ks < 4; ++ks) {
        bf16x8 ah, al;
        load_split8(&gsh[wv * 16 + lrow][ks * 32 + quad * 8], ah, al);
        #pragma unroll
        for (int nc = 0; nc < 8; ++nc) {
            int bi = (ks * 128 + nc * 16 + lrow) * 4 + quad;
            bf16x8 bh = ph[bi], bl = pl[bi];
            acc[nc] = __builtin_amdgcn_mfma_f32_16x16x32_bf16(ah, bl, acc[nc], 0, 0, 0);
            acc[nc] = __builtin_amdgcn_mfma_f32_16x16x32_bf16(al, bh, acc[nc], 0, 0, 0);
            acc[nc] = __builtin_amdgcn_mfma_f32_16x16x32_bf16(ah, bh, acc[nc], 0, 0, 0);
        }
    }

    #pragma unroll
    for (int nc = 0; nc < 8; ++nc) {
        #pragma unroll
        for (int r = 0; r < 4; ++r)
            out[(size_t)(p0 + wv * 16 + quad * 4 + r) * HC + nc * 16 + lrow] = acc[nc][r];
    }
}

// ---------------------------------------------------------------------------
extern "C" void kernel_launch(void* const* d_in, const int* in_sizes, int n_in,
                              void* d_out, int out_size, void* d_ws, size_t ws_size,
                              hipStream_t stream)
{
    const float* z  = (const float*)d_in[0];
    const float* ls = (const float*)d_in[1];
    const float* lb = (const float*)d_in[2];
    const float* Wq = (const float*)d_in[3];
    const float* Wk = (const float*)d_in[4];
    const float* Wv = (const float*)d_in[5];
    const float* Wb = (const float*)d_in[6];
    const float* Wg = (const float*)d_in[7];
    const float* Wo = (const float*)d_in[8];

    float* ws = (float*)d_ws;
    const size_t BIG = (size_t)NPIX * HC;
    unsigned* q_pk  = (unsigned*)ws;
    unsigned* k_pk  = (unsigned*)(ws + BIG);
    unsigned* v_pk  = (unsigned*)(ws + 2 * BIG);
    float* g_ws     = ws + 3 * BIG;
    float* go_ws    = ws + 4 * BIG;
    float* bias_n   = ws + 5 * BIG;                            // NH*NPIX floats
    bf16x8* pk      = (bf16x8*)(bias_n + (size_t)NH * NPIX);   // 5 x 64 KB packs

    pack_w_kernel<<<40, 256, 0, stream>>>(Wq, Wk, Wv, Wg, Wo, pk);
    ln_proj_kernel<<<NPIX / 32, 256, 0, stream>>>(z, ls, lb, Wb, pk,
                                                  q_pk, k_pk, v_pk, g_ws, bias_n);
    attn_kernel<<<NN * NH, 256, 0, stream>>>(q_pk, k_pk, v_pk, g_ws, bias_n, go_ws);
    outproj_kernel<<<NPIX / 64, 256, 0, stream>>>(go_ws, pk, (float*)d_out);
}

// Round 3
// 246.548 us; speedup vs baseline: 1.1030x; 1.0308x over previous
//
#include <hip/hip_runtime.h>
#include <math.h>

#define NN 256
#define CZ 128
#define NH 4
#define CH 32
#define HC 128
#define NPIX (NN*NN)
#define L2E   1.4426950408889634f
#define SCALE2 (0.17677669529663687f * 1.4426950408889634f)   // (1/sqrt(32))*log2e

typedef __attribute__((ext_vector_type(8))) short bf16x8;   // 8 bf16 (4 VGPRs)
typedef __attribute__((ext_vector_type(4))) float fx4;      // MFMA accumulator
typedef __attribute__((ext_vector_type(4))) unsigned u32x4;

// --- cheap truncation split: x ~= hi + lo, total err ~2^-16 relative ---
__device__ __forceinline__ unsigned pack_hl(float x) {
    unsigned b  = __builtin_bit_cast(unsigned, x);
    unsigned hb = b & 0xFFFF0000u;
    float r = x - __builtin_bit_cast(float, hb);
    return hb | (__builtin_bit_cast(unsigned, r) >> 16);   // hi in top16, lo in bottom16
}
// load 8 consecutive floats -> hi/lo bf16x8 fragments (trunc split, ~4 VALU/elem)
__device__ __forceinline__ void load_split8(const float* p, bf16x8& h, bf16x8& l) {
    float4 x0 = *(const float4*)p;
    float4 x1 = *(const float4*)(p + 4);
    float xs[8] = {x0.x, x0.y, x0.z, x0.w, x1.x, x1.y, x1.z, x1.w};
    #pragma unroll
    for (int j = 0; j < 8; ++j) {
        unsigned b  = __builtin_bit_cast(unsigned, xs[j]);
        unsigned hb = b & 0xFFFF0000u;
        float r = xs[j] - __builtin_bit_cast(float, hb);
        h[j] = (short)(hb >> 16);
        l[j] = (short)(__builtin_bit_cast(unsigned, r) >> 16);
    }
}
// deinterleave 8 packed uint32 (hi|lo) held in registers -> hi/lo bf16x8 frags
__device__ __forceinline__ void deint_raw(u32x4 e0, u32x4 e1, bf16x8& h, bf16x8& l) {
    unsigned es[8] = {e0[0], e0[1], e0[2], e0[3], e1[0], e1[1], e1[2], e1[3]};
    unsigned hw[4], lw[4];
    #pragma unroll
    for (int j = 0; j < 4; ++j) {
        unsigned a = es[2 * j], b = es[2 * j + 1];
        hw[j] = (a >> 16) | (b & 0xFFFF0000u);
        lw[j] = (a & 0x0000FFFFu) | (b << 16);
    }
    h = __builtin_bit_cast(bf16x8, u32x4{hw[0], hw[1], hw[2], hw[3]});
    l = __builtin_bit_cast(bf16x8, u32x4{lw[0], lw[1], lw[2], lw[3]});
}
// load 8 packed uint32 (hi|lo) -> hi/lo bf16x8 fragments
__device__ __forceinline__ void deint8(const unsigned* p, bf16x8& h, bf16x8& l) {
    u32x4 e0 = *(const u32x4*)p;
    u32x4 e1 = *(const u32x4*)(p + 4);
    deint_raw(e0, e1, h, l);
}

// 2x2x2 quad transpose across lanes: given per-lane words (x = value of tile0,
// y = value of tile1) indexed by quad q = lane>>4, produce
//   x' = [x(q0), x(q2), y(q0), y(q2)],  y' = [x(q1), x(q3), y(q1), y(q3)].
// Implemented with gfx950 dual-dest lane swaps (no LDS, no lgkmcnt).
__device__ __forceinline__ void qtrans(unsigned &x, unsigned &y) {
#if __has_builtin(__builtin_amdgcn_permlane32_swap) && __has_builtin(__builtin_amdgcn_permlane16_swap)
    {
        auto r = __builtin_amdgcn_permlane32_swap(x, y, false, false);
        x = r[0]; y = r[1];
    }
    {
        auto r = __builtin_amdgcn_permlane16_swap(x, y, false, false);
        x = r[0]; y = r[1];
    }
#else
    asm("v_permlane32_swap_b32 %0, %1\n\t"
        "v_permlane16_swap_b32 %0, %1" : "+v"(x), "+v"(y));
#endif
}

// ---------------------------------------------------------------------------
// Kernel 0: pack weights into MFMA B-fragment layout, bf16 hi/lo planes.
// B-frag (16x16x32): lane holds B[k][n], n=lane&15, k=quad*8+j.
// entry index: (kstep*128 + n)*4 + quad. 0=Wq 1=Wk 2=Wv 3=Wg 4=Wo.
// ---------------------------------------------------------------------------
__global__ __launch_bounds__(256) void pack_w_kernel(
    const float* __restrict__ Wq, const float* __restrict__ Wk,
    const float* __restrict__ Wv, const float* __restrict__ Wg,
    const float* __restrict__ Wo, bf16x8* __restrict__ pk)
{
    int id  = blockIdx.x * 256 + threadIdx.x;
    int mid = id >> 11;
    int e   = id & 2047;
    const float* W = (mid == 0) ? Wq : (mid == 1) ? Wk : (mid == 2) ? Wv : (mid == 3) ? Wg : Wo;
    int quad = e & 3, n = (e >> 2) & 127, ks = e >> 9;
    int k0 = ks * 32 + quad * 8;
    bf16x8 h, l;
    #pragma unroll
    for (int j = 0; j < 8; ++j) {
        float x = W[(size_t)(k0 + j) * 128 + n];
        unsigned b  = __builtin_bit_cast(unsigned, x);
        unsigned hb = b & 0xFFFF0000u;
        float r = x - __builtin_bit_cast(float, hb);
        h[j] = (short)(hb >> 16);
        l[j] = (short)(__builtin_bit_cast(unsigned, r) >> 16);
    }
    pk[(size_t)mid * 4096 + e]        = h;
    pk[(size_t)mid * 4096 + 2048 + e] = l;
}

// ---------------------------------------------------------------------------
// Kernel 1: fused LayerNorm + projections via split-bf16 MFMA.
// Outputs (hi|lo packed uint32 unless noted):
//   q_pk [i][h][j][c]    k_pk [i][h][j][c]    v_pk [i][h][c][j]
//   g_ws [pix][h*32+c] (fp32, sigmoid applied)
//   bias_n [h][n1=query][n2=key] (fp32, * log2e) -- natural order, coalesced
// ---------------------------------------------------------------------------
__global__ __launch_bounds__(256) void ln_proj_kernel(
    const float* __restrict__ z, const float* __restrict__ ls, const float* __restrict__ lb,
    const float* __restrict__ Wb, const bf16x8* __restrict__ pk,
    unsigned* __restrict__ q_pk, unsigned* __restrict__ k_pk, unsigned* __restrict__ v_pk,
    float* __restrict__ g_ws, float* __restrict__ bias_n)
{
    __shared__ float zsh[32][132];
    __shared__ float rsum[256], rsq[256];
    __shared__ float pmu[32], prs[32];

    const int t  = threadIdx.x;
    const int p0 = blockIdx.x * 32;
    const int i  = p0 >> 8;
    const int j0 = p0 & 255;

    const float4* z4 = (const float4*)(z + (size_t)p0 * CZ);
    #pragma unroll
    for (int r = 0; r < 4; ++r) {
        int idx4 = t + 256 * r;
        int p = idx4 >> 5, pos = idx4 & 31;
        *(float4*)&zsh[p][pos * 4] = z4[idx4];
    }
    __syncthreads();

    {
        int p = t >> 3, sg = t & 7;
        float s = 0.f, q = 0.f;
        #pragma unroll
        for (int u = 0; u < 16; ++u) { float x = zsh[p][sg * 16 + u]; s += x; q += x * x; }
        rsum[t] = s; rsq[t] = q;
    }
    __syncthreads();
    if (t < 32) {
        float s = 0.f, q = 0.f;
        #pragma unroll
        for (int g = 0; g < 8; ++g) { s += rsum[t * 8 + g]; q += rsq[t * 8 + g]; }
        float mu  = s * (1.0f / 128.0f);
        float var = q * (1.0f / 128.0f) - mu * mu;
        float a   = var + 1e-5f;
        float r   = rsqrtf(a);
        r = r * (1.5f - 0.5f * a * r * r);
        pmu[t] = mu; prs[t] = r;
    }
    __syncthreads();

    #pragma unroll
    for (int r4 = 0; r4 < 4; ++r4) {
        int idx4 = t + 256 * r4;
        int p = idx4 >> 5, pos = idx4 & 31;
        float4 v  = *(float4*)&zsh[p][pos * 4];
        float4 s4 = ((const float4*)ls)[pos];
        float4 b4 = ((const float4*)lb)[pos];
        float mu = pmu[p], rs = prs[p];
        v.x = (v.x - mu) * rs * s4.x + b4.x;
        v.y = (v.y - mu) * rs * s4.y + b4.y;
        v.z = (v.z - mu) * rs * s4.z + b4.z;
        v.w = (v.w - mu) * rs * s4.w + b4.w;
        *(float4*)&zsh[p][pos * 4] = v;
    }
    __syncthreads();

    const int wv = t >> 6, lane = t & 63;
    const int lrow = lane & 15, quad = lane >> 4;
    const bf16x8* ph = pk + (size_t)wv * 4096;
    const bf16x8* pl = ph + 2048;

    fx4 acc[2][8];
    #pragma unroll
    for (int mr = 0; mr < 2; ++mr)
        #pragma unroll
        for (int nc = 0; nc < 8; ++nc)
            acc[mr][nc] = fx4{0.f, 0.f, 0.f, 0.f};

    #pragma unroll
    for (int ks = 0; ks < 4; ++ks) {
        bf16x8 ah[2], al[2];
        #pragma unroll
        for (int mr = 0; mr < 2; ++mr)
            load_split8(&zsh[mr * 16 + lrow][ks * 32 + quad * 8], ah[mr], al[mr]);
        #pragma unroll
        for (int nc = 0; nc < 8; ++nc) {
            int bi = (ks * 128 + nc * 16 + lrow) * 4 + quad;
            bf16x8 bh = ph[bi], bl = pl[bi];
            #pragma unroll
            for (int mr = 0; mr < 2; ++mr) {
                acc[mr][nc] = __builtin_amdgcn_mfma_f32_16x16x32_bf16(ah[mr], bl, acc[mr][nc], 0, 0, 0);
                acc[mr][nc] = __builtin_amdgcn_mfma_f32_16x16x32_bf16(al[mr], bh, acc[mr][nc], 0, 0, 0);
                acc[mr][nc] = __builtin_amdgcn_mfma_f32_16x16x32_bf16(ah[mr], bh, acc[mr][nc], 0, 0, 0);
            }
        }
    }

    // epilogue: C layout col=lane&15, row=quad*4+reg
    #pragma unroll
    for (int mr = 0; mr < 2; ++mr) {
        #pragma unroll
        for (int nc = 0; nc < 8; ++nc) {
            int cg = nc * 16 + lrow;          // channel 0..127
            int h = cg >> 5, cc = cg & 31;
            int jl = mr * 16 + quad * 4;      // local pixel base (4 consecutive)
            fx4 a = acc[mr][nc];
            if (wv == 0) {                    // q packed [j][c]
                unsigned* qp = q_pk + ((size_t)(i * NH + h) * NN + j0 + jl) * CH + cc;
                #pragma unroll
                for (int r = 0; r < 4; ++r) qp[r * CH] = pack_hl(a[r]);
            } else if (wv == 1) {             // k packed [j][c]
                unsigned* kp = k_pk + ((size_t)(i * NH + h) * NN + j0 + jl) * CH + cc;
                #pragma unroll
                for (int r = 0; r < 4; ++r) kp[r * CH] = pack_hl(a[r]);
            } else if (wv == 2) {             // v packed transposed [c][j]
                u32x4 e = {pack_hl(a[0]), pack_hl(a[1]), pack_hl(a[2]), pack_hl(a[3])};
                *(u32x4*)(v_pk + ((size_t)(i * NH + h) * CH + cc) * NN + j0 + jl) = e;
            } else {                          // g (fp32)
                float* gp = g_ws + (size_t)(p0 + jl) * HC + cg;
                #pragma unroll
                for (int r = 0; r < 4; ++r) gp[r * HC] = 1.0f / (1.0f + __expf(-a[r]));
            }
        }
    }

    // bias = zn @ Wb * log2e; natural layout [h][n1=query=i][n2=key=j0+p], coalesced
    if (t < 128) {
        int hh = t >> 5, p = t & 31;
        float b = 0.f;
        for (int d = 0; d < 128; ++d) b = fmaf(zsh[p][d], Wb[d * 4 + hh], b);
        bias_n[(size_t)hh * NPIX + (size_t)i * NN + j0 + p] = b * L2E;
    }
}

// ---------------------------------------------------------------------------
// Kernel 2: MFMA flash attention. Block = one (i,h), 4 waves x 64 queries.
// Phase-batched software pipeline (round-3): per kb-iter, (1) issue ALL global
// loads first (V raw, 8x bias float4, NEXT-iteration K raw prefetch), (2) deint
// K (VALU covers load latency), (3) ALL 8 QK score tiles as independent 3-MFMA
// chains, (4) deint V, (5) ALL exp2/pack, (6) ALL qtrans (permlane, no LDS),
// (7) ALL 8 PV chains. Same arithmetic/order per value as round-2 -> absmax
// bit-identical. Registers deliberately grow (~2 waves/SIMD, which is the
// effective occupancy anyway) to let independent chains stay live.
// NOTE: plain __launch_bounds__(256) -- (256,4) forced 64-VGPR cap + scratch
// spill (round-1 regression, +37 MB/dispatch scratch traffic).
// ---------------------------------------------------------------------------
__global__ __launch_bounds__(256) void attn_kernel(
    const unsigned* __restrict__ q_pk, const unsigned* __restrict__ k_pk,
    const unsigned* __restrict__ v_pk, const float* __restrict__ g_ws,
    const float* __restrict__ bias_n, float* __restrict__ go_ws)
{
    const int t = threadIdx.x;
    const int wv = t >> 6, lane = t & 63;
    const int lrow = lane & 15, quad = lane >> 4;
    const int h = blockIdx.x & 3, i = blockIdx.x >> 2;
    const int qb = wv * 64;

    const unsigned* qs = q_pk + (size_t)(i * NH + h) * NN * CH;
    const unsigned* ks = k_pk + (size_t)(i * NH + h) * NN * CH;
    const unsigned* vs = v_pk + (size_t)(i * NH + h) * CH * NN;
    const float*    bs = bias_n + (size_t)h * NPIX;

    // Q B-frags (hi/lo), 4 query-tiles: lane holds Q^T[k=c=quad*8+j][n=query=lrow]
    bf16x8 qh[4], ql[4];
    #pragma unroll
    for (int nt = 0; nt < 4; ++nt)
        deint8(qs + (size_t)(qb + nt * 16 + lrow) * CH + quad * 8, qh[nt], ql[nt]);

    // raw K words for kb = 0 (software-pipelined: loaded one iteration ahead)
    u32x4 krA[2], krB[2];
    #pragma unroll
    for (int mt = 0; mt < 2; ++mt) {
        const u32x4* kp = (const u32x4*)(ks + (size_t)(mt * 16 + lrow) * CH + quad * 8);
        krA[mt] = kp[0]; krB[mt] = kp[1];
    }

    fx4 oacc[2][4];   // [c-tile][q-tile], O^T C-layout
    #pragma unroll
    for (int ct = 0; ct < 2; ++ct)
        #pragma unroll
        for (int nt = 0; nt < 4; ++nt)
            oacc[ct][nt] = fx4{0.f, 0.f, 0.f, 0.f};
    float lsum[4] = {0.f, 0.f, 0.f, 0.f};

    for (int kb = 0; kb < NN; kb += 32) {
        // ---- issue all global loads up front ----
        // V raw (current kb): lane holds V^T[m=c=lrow][k=key=quad*8+j]
        u32x4 vrA[2], vrB[2];
        #pragma unroll
        for (int ct = 0; ct < 2; ++ct) {
            const u32x4* vp = (const u32x4*)(vs + (size_t)(ct * 16 + lrow) * NN + kb + quad * 8);
            vrA[ct] = vp[0]; vrB[ct] = vp[1];
        }
        // bias (current kb), all 8 tiles
        float4 bv[4][2];
        #pragma unroll
        for (int nt = 0; nt < 4; ++nt)
            #pragma unroll
            for (int mt = 0; mt < 2; ++mt)
                bv[nt][mt] = *(const float4*)(bs + (size_t)(qb + nt * 16 + lrow) * NN
                                                 + kb + mt * 16 + quad * 4);
        // K raw prefetch for NEXT kb (wraps harmlessly on last iter)
        const int kb2 = (kb + 32) & (NN - 1);
        u32x4 nkA[2], nkB[2];
        #pragma unroll
        for (int mt = 0; mt < 2; ++mt) {
            const u32x4* kp = (const u32x4*)(ks + (size_t)(kb2 + mt * 16 + lrow) * CH + quad * 8);
            nkA[mt] = kp[0]; nkB[mt] = kp[1];
        }

        // ---- deint current K (VALU; covers V/bias load latency) ----
        bf16x8 kh[2], kl_[2];
        #pragma unroll
        for (int mt = 0; mt < 2; ++mt)
            deint_raw(krA[mt], krB[mt], kh[mt], kl_[mt]);

        // ---- phase 1: all 8 QK score tiles (independent 3-MFMA chains) ----
        fx4 sv[4][2];
        __builtin_amdgcn_s_setprio(1);
        #pragma unroll
        for (int nt = 0; nt < 4; ++nt) {
            #pragma unroll
            for (int mt = 0; mt < 2; ++mt) {
                fx4 s = fx4{0.f, 0.f, 0.f, 0.f};
                s = __builtin_amdgcn_mfma_f32_16x16x32_bf16(kh[mt],  ql[nt], s, 0, 0, 0);
                s = __builtin_amdgcn_mfma_f32_16x16x32_bf16(kl_[mt], qh[nt], s, 0, 0, 0);
                s = __builtin_amdgcn_mfma_f32_16x16x32_bf16(kh[mt],  qh[nt], s, 0, 0, 0);
                sv[nt][mt] = s;
            }
        }
        __builtin_amdgcn_s_setprio(0);

        // ---- deint V (needed only in phase 4) ----
        bf16x8 vh[2], vl[2];
        #pragma unroll
        for (int ct = 0; ct < 2; ++ct)
            deint_raw(vrA[ct], vrB[ct], vh[ct], vl[ct]);

        // ---- phase 2: exp2 + hi/lo pack for all 8 tiles ----
        unsigned w0h[4][2], w1h[4][2], w0l[4][2], w1l[4][2];
        #pragma unroll
        for (int nt = 0; nt < 4; ++nt) {
            #pragma unroll
            for (int mt = 0; mt < 2; ++mt) {
                fx4 s = sv[nt][mt];
                float4 b4 = bv[nt][mt];
                float e0 = exp2f(fmaf(s[0], SCALE2, b4.x));
                float e1 = exp2f(fmaf(s[1], SCALE2, b4.y));
                float e2 = exp2f(fmaf(s[2], SCALE2, b4.z));
                float e3 = exp2f(fmaf(s[3], SCALE2, b4.w));
                lsum[nt] += (e0 + e1) + (e2 + e3);

                unsigned b0 = __builtin_bit_cast(unsigned, e0);
                unsigned b1 = __builtin_bit_cast(unsigned, e1);
                unsigned b2 = __builtin_bit_cast(unsigned, e2);
                unsigned b3 = __builtin_bit_cast(unsigned, e3);
                unsigned h01 = (b0 >> 16) | (b1 & 0xFFFF0000u);
                unsigned h23 = (b2 >> 16) | (b3 & 0xFFFF0000u);
                float r0 = e0 - __builtin_bit_cast(float, b0 & 0xFFFF0000u);
                float r1 = e1 - __builtin_bit_cast(float, b1 & 0xFFFF0000u);
                float r2 = e2 - __builtin_bit_cast(float, b2 & 0xFFFF0000u);
                float r3 = e3 - __builtin_bit_cast(float, b3 & 0xFFFF0000u);
                unsigned l01 = (__builtin_bit_cast(unsigned, r0) >> 16)
                             | (__builtin_bit_cast(unsigned, r1) & 0xFFFF0000u);
                unsigned l23 = (__builtin_bit_cast(unsigned, r2) >> 16)
                             | (__builtin_bit_cast(unsigned, r3) & 0xFFFF0000u);
                w0h[nt][mt] = h01; w1h[nt][mt] = h23;
                w0l[nt][mt] = l01; w1l[nt][mt] = l23;
            }
        }

        // ---- phase 3: C-frag -> B-frag quad transposes (in-register) ----
        #pragma unroll
        for (int nt = 0; nt < 4; ++nt) {
            qtrans(w0h[nt][0], w0h[nt][1]);
            qtrans(w1h[nt][0], w1h[nt][1]);
            qtrans(w0l[nt][0], w0l[nt][1]);
            qtrans(w1l[nt][0], w1l[nt][1]);
        }

        // ---- phase 4: all 8 PV chains ----
        __builtin_amdgcn_s_setprio(1);
        #pragma unroll
        for (int nt = 0; nt < 4; ++nt) {
            bf16x8 pbh = __builtin_bit_cast(bf16x8,
                u32x4{w0h[nt][0], w1h[nt][0], w0h[nt][1], w1h[nt][1]});
            bf16x8 pbl = __builtin_bit_cast(bf16x8,
                u32x4{w0l[nt][0], w1l[nt][0], w0l[nt][1], w1l[nt][1]});
            #pragma unroll
            for (int ct = 0; ct < 2; ++ct) {
                oacc[ct][nt] = __builtin_amdgcn_mfma_f32_16x16x32_bf16(vh[ct], pbl, oacc[ct][nt], 0, 0, 0);
                oacc[ct][nt] = __builtin_amdgcn_mfma_f32_16x16x32_bf16(vl[ct], pbh, oacc[ct][nt], 0, 0, 0);
                oacc[ct][nt] = __builtin_amdgcn_mfma_f32_16x16x32_bf16(vh[ct], pbh, oacc[ct][nt], 0, 0, 0);
            }
        }
        __builtin_amdgcn_s_setprio(0);

        // rotate prefetched K into place
        #pragma unroll
        for (int mt = 0; mt < 2; ++mt) { krA[mt] = nkA[mt]; krB[mt] = nkB[mt]; }
    }

    // epilogue: reduce l over quads, gate, store. O^T: col=query=lrow, row=c=quad*4+r
    #pragma unroll
    for (int nt = 0; nt < 4; ++nt) {
        float s = lsum[nt];
        s += __shfl_xor(s, 16, 64);
        s += __shfl_xor(s, 32, 64);
        float inv = 1.0f / s;
        size_t pix = (size_t)i * NN + qb + nt * 16 + lrow;
        #pragma unroll
        for (int ct = 0; ct < 2; ++ct) {
            const float* gp = g_ws + pix * HC + h * CH + ct * 16 + quad * 4;
            float4 g4 = *(const float4*)gp;
            fx4 o = oacc[ct][nt];
            float4 r;
            r.x = g4.x * o[0] * inv;
            r.y = g4.y * o[1] * inv;
            r.z = g4.z * o[2] * inv;
            r.w = g4.w * o[3] * inv;
            *(float4*)(go_ws + pix * HC + h * CH + ct * 16 + quad * 4) = r;
        }
    }
}

// ---------------------------------------------------------------------------
// Kernel 3: out = go @ Wo via split-bf16 MFMA.
// ---------------------------------------------------------------------------
__global__ __launch_bounds__(256) void outproj_kernel(
    const float* __restrict__ go_ws, const bf16x8* __restrict__ pk, float* __restrict__ out)
{
    __shared__ float gsh[64][132];
    const int t  = threadIdx.x;
    const int p0 = blockIdx.x * 64;

    const float4* g4 = (const float4*)(go_ws + (size_t)p0 * HC);
    #pragma unroll
    for (int r = 0; r < 8; ++r) {
        int idx4 = t + 256 * r;
        int p = idx4 >> 5, pos = idx4 & 31;
        *(float4*)&gsh[p][pos * 4] = g4[idx4];
    }
    __syncthreads();

    const int wv = t >> 6, lane = t & 63;
    const int lrow = lane & 15, quad = lane >> 4;
    const bf16x8* ph = pk + (size_t)4 * 4096;   // Wo
    const bf16x8* pl = ph + 2048;

    fx4 acc[8];
    #pragma unroll
    for (int nc = 0; nc < 8; ++nc) acc[nc] = fx4{0.f, 0.f, 0.f, 0.f};

    #pragma unroll
    for (int ks = 0; ks < 4; ++ks) {
        bf16x8 ah, al;
        load_split8(&gsh[wv * 16 + lrow][ks * 32 + quad * 8], ah, al);
        #pragma unroll
        for (int nc = 0; nc < 8; ++nc) {
            int bi = (ks * 128 + nc * 16 + lrow) * 4 + quad;
            bf16x8 bh = ph[bi], bl = pl[bi];
            acc[nc] = __builtin_amdgcn_mfma_f32_16x16x32_bf16(ah, bl, acc[nc], 0, 0, 0);
            acc[nc] = __builtin_amdgcn_mfma_f32_16x16x32_bf16(al, bh, acc[nc], 0, 0, 0);
            acc[nc] = __builtin_amdgcn_mfma_f32_16x16x32_bf16(ah, bh, acc[nc], 0, 0, 0);
        }
    }

    #pragma unroll
    for (int nc = 0; nc < 8; ++nc) {
        #pragma unroll
        for (int r = 0; r < 4; ++r)
            out[(size_t)(p0 + wv * 16 + quad * 4 + r) * HC + nc * 16 + lrow] = acc[nc][r];
    }
}

// ---------------------------------------------------------------------------
extern "C" void kernel_launch(void* const* d_in, const int* in_sizes, int n_in,
                              void* d_out, int out_size, void* d_ws, size_t ws_size,
                              hipStream_t stream)
{
    const float* z  = (const float*)d_in[0];
    const float* ls = (const float*)d_in[1];
    const float* lb = (const float*)d_in[2];
    const float* Wq = (const float*)d_in[3];
    const float* Wk = (const float*)d_in[4];
    const float* Wv = (const float*)d_in[5];
    const float* Wb = (const float*)d_in[6];
    const float* Wg = (const float*)d_in[7];
    const float* Wo = (const float*)d_in[8];

    float* ws = (float*)d_ws;
    const size_t BIG = (size_t)NPIX * HC;
    unsigned* q_pk  = (unsigned*)ws;
    unsigned* k_pk  = (unsigned*)(ws + BIG);
    unsigned* v_pk  = (unsigned*)(ws + 2 * BIG);
    float* g_ws     = ws + 3 * BIG;
    float* go_ws    = ws + 4 * BIG;
    float* bias_n   = ws + 5 * BIG;                            // NH*NPIX floats
    bf16x8* pk      = (bf16x8*)(bias_n + (size_t)NH * NPIX);   // 5 x 64 KB packs

    pack_w_kernel<<<40, 256, 0, stream>>>(Wq, Wk, Wv, Wg, Wo, pk);
    ln_proj_kernel<<<NPIX / 32, 256, 0, stream>>>(z, ls, lb, Wb, pk,
                                                  q_pk, k_pk, v_pk, g_ws, bias_n);
    attn_kernel<<<NN * NH, 256, 0, stream>>>(q_pk, k_pk, v_pk, g_ws, bias_n, go_ws);
    outproj_kernel<<<NPIX / 64, 256, 0, stream>>>(go_ws, pk, (float*)d_out);
}

// Round 4
// 246.173 us; speedup vs baseline: 1.1047x; 1.0015x over previous
//
#include <hip/hip_runtime.h>
#include <math.h>

#define NN 256
#define CZ 128
#define NH 4
#define CH 32
#define HC 128
#define NPIX (NN*NN)
#define L2E   1.4426950408889634f
#define SCALE2 (0.17677669529663687f * 1.4426950408889634f)   // (1/sqrt(32))*log2e

typedef __attribute__((ext_vector_type(8))) short bf16x8;   // 8 bf16 (4 VGPRs)
typedef __attribute__((ext_vector_type(4))) float fx4;      // MFMA accumulator
typedef __attribute__((ext_vector_type(4))) unsigned u32x4;

// --- cheap truncation split: x ~= hi + lo, total err ~2^-16 relative ---
__device__ __forceinline__ unsigned pack_hl(float x) {
    unsigned b  = __builtin_bit_cast(unsigned, x);
    unsigned hb = b & 0xFFFF0000u;
    float r = x - __builtin_bit_cast(float, hb);
    return hb | (__builtin_bit_cast(unsigned, r) >> 16);   // hi in top16, lo in bottom16
}
// load 8 consecutive floats -> hi/lo bf16x8 fragments (trunc split, ~4 VALU/elem)
__device__ __forceinline__ void load_split8(const float* p, bf16x8& h, bf16x8& l) {
    float4 x0 = *(const float4*)p;
    float4 x1 = *(const float4*)(p + 4);
    float xs[8] = {x0.x, x0.y, x0.z, x0.w, x1.x, x1.y, x1.z, x1.w};
    #pragma unroll
    for (int j = 0; j < 8; ++j) {
        unsigned b  = __builtin_bit_cast(unsigned, xs[j]);
        unsigned hb = b & 0xFFFF0000u;
        float r = xs[j] - __builtin_bit_cast(float, hb);
        h[j] = (short)(hb >> 16);
        l[j] = (short)(__builtin_bit_cast(unsigned, r) >> 16);
    }
}
// deinterleave 8 packed uint32 (hi|lo) held in registers -> hi/lo bf16x8 frags
__device__ __forceinline__ void deint_raw(u32x4 e0, u32x4 e1, bf16x8& h, bf16x8& l) {
    unsigned es[8] = {e0[0], e0[1], e0[2], e0[3], e1[0], e1[1], e1[2], e1[3]};
    unsigned hw[4], lw[4];
    #pragma unroll
    for (int j = 0; j < 4; ++j) {
        unsigned a = es[2 * j], b = es[2 * j + 1];
        hw[j] = (a >> 16) | (b & 0xFFFF0000u);
        lw[j] = (a & 0x0000FFFFu) | (b << 16);
    }
    h = __builtin_bit_cast(bf16x8, u32x4{hw[0], hw[1], hw[2], hw[3]});
    l = __builtin_bit_cast(bf16x8, u32x4{lw[0], lw[1], lw[2], lw[3]});
}
// load 8 packed uint32 (hi|lo) -> hi/lo bf16x8 fragments
__device__ __forceinline__ void deint8(const unsigned* p, bf16x8& h, bf16x8& l) {
    u32x4 e0 = *(const u32x4*)p;
    u32x4 e1 = *(const u32x4*)(p + 4);
    deint_raw(e0, e1, h, l);
}

// 2x2x2 quad transpose across lanes (gfx950 dual-dest lane swaps, no LDS).
__device__ __forceinline__ void qtrans(unsigned &x, unsigned &y) {
#if __has_builtin(__builtin_amdgcn_permlane32_swap) && __has_builtin(__builtin_amdgcn_permlane16_swap)
    {
        auto r = __builtin_amdgcn_permlane32_swap(x, y, false, false);
        x = r[0]; y = r[1];
    }
    {
        auto r = __builtin_amdgcn_permlane16_swap(x, y, false, false);
        x = r[0]; y = r[1];
    }
#else
    asm("v_permlane32_swap_b32 %0, %1\n\t"
        "v_permlane16_swap_b32 %0, %1" : "+v"(x), "+v"(y));
#endif
}

// ---------------------------------------------------------------------------
// Kernel 0: pack weights into MFMA B-fragment layout, bf16 hi/lo planes.
// B-frag (16x16x32): lane holds B[k][n], n=lane&15, k=quad*8+j.
// entry index: (kstep*128 + n)*4 + quad. 0=Wq 1=Wk 2=Wv 3=Wg 4=Wo.
// ---------------------------------------------------------------------------
__global__ __launch_bounds__(256) void pack_w_kernel(
    const float* __restrict__ Wq, const float* __restrict__ Wk,
    const float* __restrict__ Wv, const float* __restrict__ Wg,
    const float* __restrict__ Wo, bf16x8* __restrict__ pk)
{
    int id  = blockIdx.x * 256 + threadIdx.x;
    int mid = id >> 11;
    int e   = id & 2047;
    const float* W = (mid == 0) ? Wq : (mid == 1) ? Wk : (mid == 2) ? Wv : (mid == 3) ? Wg : Wo;
    int quad = e & 3, n = (e >> 2) & 127, ks = e >> 9;
    int k0 = ks * 32 + quad * 8;
    bf16x8 h, l;
    #pragma unroll
    for (int j = 0; j < 8; ++j) {
        float x = W[(size_t)(k0 + j) * 128 + n];
        unsigned b  = __builtin_bit_cast(unsigned, x);
        unsigned hb = b & 0xFFFF0000u;
        float r = x - __builtin_bit_cast(float, hb);
        h[j] = (short)(hb >> 16);
        l[j] = (short)(__builtin_bit_cast(unsigned, r) >> 16);
    }
    pk[(size_t)mid * 4096 + e]        = h;
    pk[(size_t)mid * 4096 + 2048 + e] = l;
}

// ---------------------------------------------------------------------------
// Kernel 1: fused LayerNorm + projections via split-bf16 MFMA.
// Round-4 restructure: LN stats per-thread in REGISTERS (each thread owns 16ch
// of one pixel) + 3-step shuffle reduce over the 8 threads/pixel; normalize
// from registers; ONE barrier total (was 4). Wb staged to LDS. Bias tail
// parallelized 2 threads/output (64-deep halves + pair shuffle).
// Outputs unchanged: q_pk/k_pk/v_pk (hi|lo u32), g_ws fp32 sigmoid,
// bias_n [h][query][key] * log2e.
// ---------------------------------------------------------------------------
__global__ __launch_bounds__(256) void ln_proj_kernel(
    const float* __restrict__ z, const float* __restrict__ ls, const float* __restrict__ lb,
    const float* __restrict__ Wb, const bf16x8* __restrict__ pk,
    unsigned* __restrict__ q_pk, unsigned* __restrict__ k_pk, unsigned* __restrict__ v_pk,
    float* __restrict__ g_ws, float* __restrict__ bias_n)
{
    __shared__ float zsh[32][132];
    __shared__ float wbsh[512];

    const int t  = threadIdx.x;
    const int p0 = blockIdx.x * 32;
    const int i  = p0 >> 8;
    const int j0 = p0 & 255;

    // stage Wb (128x4 floats) into LDS alongside the z loads
    wbsh[t]       = Wb[t];
    wbsh[t + 256] = Wb[t + 256];

    // thread owns 16 channels (sub*16..) of pixel p = t>>3
    const int p = t >> 3, sub = t & 7;
    float4 zv[4];
    {
        const float4* zp = (const float4*)(z + (size_t)(p0 + p) * CZ + sub * 16);
        #pragma unroll
        for (int r = 0; r < 4; ++r) zv[r] = zp[r];
    }
    float s = 0.f, q = 0.f;
    #pragma unroll
    for (int r = 0; r < 4; ++r) {
        s += ((zv[r].x + zv[r].y) + (zv[r].z + zv[r].w));
        q += ((zv[r].x * zv[r].x + zv[r].y * zv[r].y)
            + (zv[r].z * zv[r].z + zv[r].w * zv[r].w));
    }
    // reduce across the 8 threads of this pixel (lane bits 0..2)
    #pragma unroll
    for (int m = 1; m <= 4; m <<= 1) {
        s += __shfl_xor(s, m, 64);
        q += __shfl_xor(q, m, 64);
    }
    {
        float mu  = s * (1.0f / 128.0f);
        float var = q * (1.0f / 128.0f) - mu * mu;
        float a   = var + 1e-5f;
        float r0  = rsqrtf(a);
        r0 = r0 * (1.5f - 0.5f * a * r0 * r0);
        #pragma unroll
        for (int r = 0; r < 4; ++r) {
            float4 s4 = ((const float4*)ls)[sub * 4 + r];
            float4 b4 = ((const float4*)lb)[sub * 4 + r];
            float4 v  = zv[r];
            v.x = (v.x - mu) * r0 * s4.x + b4.x;
            v.y = (v.y - mu) * r0 * s4.y + b4.y;
            v.z = (v.z - mu) * r0 * s4.z + b4.z;
            v.w = (v.w - mu) * r0 * s4.w + b4.w;
            *(float4*)&zsh[p][sub * 16 + r * 4] = v;
        }
    }
    __syncthreads();   // the ONLY barrier

    const int wv = t >> 6, lane = t & 63;
    const int lrow = lane & 15, quad = lane >> 4;
    const bf16x8* ph = pk + (size_t)wv * 4096;
    const bf16x8* pl = ph + 2048;

    fx4 acc[2][8];
    #pragma unroll
    for (int mr = 0; mr < 2; ++mr)
        #pragma unroll
        for (int nc = 0; nc < 8; ++nc)
            acc[mr][nc] = fx4{0.f, 0.f, 0.f, 0.f};

    #pragma unroll
    for (int ks = 0; ks < 4; ++ks) {
        bf16x8 ah[2], al[2];
        #pragma unroll
        for (int mr = 0; mr < 2; ++mr)
            load_split8(&zsh[mr * 16 + lrow][ks * 32 + quad * 8], ah[mr], al[mr]);
        #pragma unroll
        for (int nc = 0; nc < 8; ++nc) {
            int bi = (ks * 128 + nc * 16 + lrow) * 4 + quad;
            bf16x8 bh = ph[bi], bl = pl[bi];
            #pragma unroll
            for (int mr = 0; mr < 2; ++mr) {
                acc[mr][nc] = __builtin_amdgcn_mfma_f32_16x16x32_bf16(ah[mr], bl, acc[mr][nc], 0, 0, 0);
                acc[mr][nc] = __builtin_amdgcn_mfma_f32_16x16x32_bf16(al[mr], bh, acc[mr][nc], 0, 0, 0);
                acc[mr][nc] = __builtin_amdgcn_mfma_f32_16x16x32_bf16(ah[mr], bh, acc[mr][nc], 0, 0, 0);
            }
        }
    }

    // epilogue: C layout col=lane&15, row=quad*4+reg
    #pragma unroll
    for (int mr = 0; mr < 2; ++mr) {
        #pragma unroll
        for (int nc = 0; nc < 8; ++nc) {
            int cg = nc * 16 + lrow;          // channel 0..127
            int h = cg >> 5, cc = cg & 31;
            int jl = mr * 16 + quad * 4;      // local pixel base (4 consecutive)
            fx4 a = acc[mr][nc];
            if (wv == 0) {                    // q packed [j][c]
                unsigned* qp = q_pk + ((size_t)(i * NH + h) * NN + j0 + jl) * CH + cc;
                #pragma unroll
                for (int r = 0; r < 4; ++r) qp[r * CH] = pack_hl(a[r]);
            } else if (wv == 1) {             // k packed [j][c]
                unsigned* kp = k_pk + ((size_t)(i * NH + h) * NN + j0 + jl) * CH + cc;
                #pragma unroll
                for (int r = 0; r < 4; ++r) kp[r * CH] = pack_hl(a[r]);
            } else if (wv == 2) {             // v packed transposed [c][j]
                u32x4 e = {pack_hl(a[0]), pack_hl(a[1]), pack_hl(a[2]), pack_hl(a[3])};
                *(u32x4*)(v_pk + ((size_t)(i * NH + h) * CH + cc) * NN + j0 + jl) = e;
            } else {                          // g (fp32)
                float* gp = g_ws + (size_t)(p0 + jl) * HC + cg;
                #pragma unroll
                for (int r = 0; r < 4; ++r) gp[r * HC] = 1.0f / (1.0f + __expf(-a[r]));
            }
        }
    }

    // bias = zn @ Wb * log2e; 2 threads per (hh,p): 64-deep halves + pair add
    {
        int pair = t >> 1, half = t & 1;
        int hh = pair >> 5, pp = pair & 31;
        int d0 = half * 64;
        float b = 0.f;
        #pragma unroll 8
        for (int d = 0; d < 64; ++d)
            b = fmaf(zsh[pp][d0 + d], wbsh[(d0 + d) * 4 + hh], b);
        b += __shfl_xor(b, 1, 64);
        if (half == 0)
            bias_n[(size_t)hh * NPIX + (size_t)i * NN + j0 + pp] = b * L2E;
    }
}

// ---------------------------------------------------------------------------
// Kernel 2: MFMA flash attention. UNCHANGED from round 3 (control group).
// ---------------------------------------------------------------------------
__global__ __launch_bounds__(256) void attn_kernel(
    const unsigned* __restrict__ q_pk, const unsigned* __restrict__ k_pk,
    const unsigned* __restrict__ v_pk, const float* __restrict__ g_ws,
    const float* __restrict__ bias_n, float* __restrict__ go_ws)
{
    const int t = threadIdx.x;
    const int wv = t >> 6, lane = t & 63;
    const int lrow = lane & 15, quad = lane >> 4;
    const int h = blockIdx.x & 3, i = blockIdx.x >> 2;
    const int qb = wv * 64;

    const unsigned* qs = q_pk + (size_t)(i * NH + h) * NN * CH;
    const unsigned* ks = k_pk + (size_t)(i * NH + h) * NN * CH;
    const unsigned* vs = v_pk + (size_t)(i * NH + h) * CH * NN;
    const float*    bs = bias_n + (size_t)h * NPIX;

    bf16x8 qh[4], ql[4];
    #pragma unroll
    for (int nt = 0; nt < 4; ++nt)
        deint8(qs + (size_t)(qb + nt * 16 + lrow) * CH + quad * 8, qh[nt], ql[nt]);

    u32x4 krA[2], krB[2];
    #pragma unroll
    for (int mt = 0; mt < 2; ++mt) {
        const u32x4* kp = (const u32x4*)(ks + (size_t)(mt * 16 + lrow) * CH + quad * 8);
        krA[mt] = kp[0]; krB[mt] = kp[1];
    }

    fx4 oacc[2][4];
    #pragma unroll
    for (int ct = 0; ct < 2; ++ct)
        #pragma unroll
        for (int nt = 0; nt < 4; ++nt)
            oacc[ct][nt] = fx4{0.f, 0.f, 0.f, 0.f};
    float lsum[4] = {0.f, 0.f, 0.f, 0.f};

    for (int kb = 0; kb < NN; kb += 32) {
        u32x4 vrA[2], vrB[2];
        #pragma unroll
        for (int ct = 0; ct < 2; ++ct) {
            const u32x4* vp = (const u32x4*)(vs + (size_t)(ct * 16 + lrow) * NN + kb + quad * 8);
            vrA[ct] = vp[0]; vrB[ct] = vp[1];
        }
        float4 bv[4][2];
        #pragma unroll
        for (int nt = 0; nt < 4; ++nt)
            #pragma unroll
            for (int mt = 0; mt < 2; ++mt)
                bv[nt][mt] = *(const float4*)(bs + (size_t)(qb + nt * 16 + lrow) * NN
                                                 + kb + mt * 16 + quad * 4);
        const int kb2 = (kb + 32) & (NN - 1);
        u32x4 nkA[2], nkB[2];
        #pragma unroll
        for (int mt = 0; mt < 2; ++mt) {
            const u32x4* kp = (const u32x4*)(ks + (size_t)(kb2 + mt * 16 + lrow) * CH + quad * 8);
            nkA[mt] = kp[0]; nkB[mt] = kp[1];
        }

        bf16x8 kh[2], kl_[2];
        #pragma unroll
        for (int mt = 0; mt < 2; ++mt)
            deint_raw(krA[mt], krB[mt], kh[mt], kl_[mt]);

        fx4 sv[4][2];
        __builtin_amdgcn_s_setprio(1);
        #pragma unroll
        for (int nt = 0; nt < 4; ++nt) {
            #pragma unroll
            for (int mt = 0; mt < 2; ++mt) {
                fx4 s = fx4{0.f, 0.f, 0.f, 0.f};
                s = __builtin_amdgcn_mfma_f32_16x16x32_bf16(kh[mt],  ql[nt], s, 0, 0, 0);
                s = __builtin_amdgcn_mfma_f32_16x16x32_bf16(kl_[mt], qh[nt], s, 0, 0, 0);
                s = __builtin_amdgcn_mfma_f32_16x16x32_bf16(kh[mt],  qh[nt], s, 0, 0, 0);
                sv[nt][mt] = s;
            }
        }
        __builtin_amdgcn_s_setprio(0);

        bf16x8 vh[2], vl[2];
        #pragma unroll
        for (int ct = 0; ct < 2; ++ct)
            deint_raw(vrA[ct], vrB[ct], vh[ct], vl[ct]);

        unsigned w0h[4][2], w1h[4][2], w0l[4][2], w1l[4][2];
        #pragma unroll
        for (int nt = 0; nt < 4; ++nt) {
            #pragma unroll
            for (int mt = 0; mt < 2; ++mt) {
                fx4 s = sv[nt][mt];
                float4 b4 = bv[nt][mt];
                float e0 = exp2f(fmaf(s[0], SCALE2, b4.x));
                float e1 = exp2f(fmaf(s[1], SCALE2, b4.y));
                float e2 = exp2f(fmaf(s[2], SCALE2, b4.z));
                float e3 = exp2f(fmaf(s[3], SCALE2, b4.w));
                lsum[nt] += (e0 + e1) + (e2 + e3);

                unsigned b0 = __builtin_bit_cast(unsigned, e0);
                unsigned b1 = __builtin_bit_cast(unsigned, e1);
                unsigned b2 = __builtin_bit_cast(unsigned, e2);
                unsigned b3 = __builtin_bit_cast(unsigned, e3);
                unsigned h01 = (b0 >> 16) | (b1 & 0xFFFF0000u);
                unsigned h23 = (b2 >> 16) | (b3 & 0xFFFF0000u);
                float r0 = e0 - __builtin_bit_cast(float, b0 & 0xFFFF0000u);
                float r1 = e1 - __builtin_bit_cast(float, b1 & 0xFFFF0000u);
                float r2 = e2 - __builtin_bit_cast(float, b2 & 0xFFFF0000u);
                float r3 = e3 - __builtin_bit_cast(float, b3 & 0xFFFF0000u);
                unsigned l01 = (__builtin_bit_cast(unsigned, r0) >> 16)
                             | (__builtin_bit_cast(unsigned, r1) & 0xFFFF0000u);
                unsigned l23 = (__builtin_bit_cast(unsigned, r2) >> 16)
                             | (__builtin_bit_cast(unsigned, r3) & 0xFFFF0000u);
                w0h[nt][mt] = h01; w1h[nt][mt] = h23;
                w0l[nt][mt] = l01; w1l[nt][mt] = l23;
            }
        }

        #pragma unroll
        for (int nt = 0; nt < 4; ++nt) {
            qtrans(w0h[nt][0], w0h[nt][1]);
            qtrans(w1h[nt][0], w1h[nt][1]);
            qtrans(w0l[nt][0], w0l[nt][1]);
            qtrans(w1l[nt][0], w1l[nt][1]);
        }

        __builtin_amdgcn_s_setprio(1);
        #pragma unroll
        for (int nt = 0; nt < 4; ++nt) {
            bf16x8 pbh = __builtin_bit_cast(bf16x8,
                u32x4{w0h[nt][0], w1h[nt][0], w0h[nt][1], w1h[nt][1]});
            bf16x8 pbl = __builtin_bit_cast(bf16x8,
                u32x4{w0l[nt][0], w1l[nt][0], w0l[nt][1], w1l[nt][1]});
            #pragma unroll
            for (int ct = 0; ct < 2; ++ct) {
                oacc[ct][nt] = __builtin_amdgcn_mfma_f32_16x16x32_bf16(vh[ct], pbl, oacc[ct][nt], 0, 0, 0);
                oacc[ct][nt] = __builtin_amdgcn_mfma_f32_16x16x32_bf16(vl[ct], pbh, oacc[ct][nt], 0, 0, 0);
                oacc[ct][nt] = __builtin_amdgcn_mfma_f32_16x16x32_bf16(vh[ct], pbh, oacc[ct][nt], 0, 0, 0);
            }
        }
        __builtin_amdgcn_s_setprio(0);

        #pragma unroll
        for (int mt = 0; mt < 2; ++mt) { krA[mt] = nkA[mt]; krB[mt] = nkB[mt]; }
    }

    #pragma unroll
    for (int nt = 0; nt < 4; ++nt) {
        float s = lsum[nt];
        s += __shfl_xor(s, 16, 64);
        s += __shfl_xor(s, 32, 64);
        float inv = 1.0f / s;
        size_t pix = (size_t)i * NN + qb + nt * 16 + lrow;
        #pragma unroll
        for (int ct = 0; ct < 2; ++ct) {
            const float* gp = g_ws + pix * HC + h * CH + ct * 16 + quad * 4;
            float4 g4 = *(const float4*)gp;
            fx4 o = oacc[ct][nt];
            float4 r;
            r.x = g4.x * o[0] * inv;
            r.y = g4.y * o[1] * inv;
            r.z = g4.z * o[2] * inv;
            r.w = g4.w * o[3] * inv;
            *(float4*)(go_ws + pix * HC + h * CH + ct * 16 + quad * 4) = r;
        }
    }
}

// ---------------------------------------------------------------------------
// Kernel 3: out = go @ Wo via split-bf16 MFMA.
// Round-4: no LDS, no barrier -- each lane loads its own go rows directly
// (coalesced: 4 lanes/row cover 128B contiguous). Waves fully independent.
// ---------------------------------------------------------------------------
__global__ __launch_bounds__(256) void outproj_kernel(
    const float* __restrict__ go_ws, const bf16x8* __restrict__ pk, float* __restrict__ out)
{
    const int t  = threadIdx.x;
    const int p0 = blockIdx.x * 64;
    const int wv = t >> 6, lane = t & 63;
    const int lrow = lane & 15, quad = lane >> 4;
    const bf16x8* ph = pk + (size_t)4 * 4096;   // Wo
    const bf16x8* pl = ph + 2048;

    const float* grow = go_ws + (size_t)(p0 + wv * 16 + lrow) * HC + quad * 8;

    // hoist all A-fragment loads (8 x float4 per lane, independent)
    bf16x8 ah[4], al[4];
    #pragma unroll
    for (int ks = 0; ks < 4; ++ks)
        load_split8(grow + ks * 32, ah[ks], al[ks]);

    fx4 acc[8];
    #pragma unroll
    for (int nc = 0; nc < 8; ++nc) acc[nc] = fx4{0.f, 0.f, 0.f, 0.f};

    #pragma unroll
    for (int ks = 0; ks < 4; ++ks) {
        #pragma unroll
        for (int nc = 0; nc < 8; ++nc) {
            int bi = (ks * 128 + nc * 16 + lrow) * 4 + quad;
            bf16x8 bh = ph[bi], bl = pl[bi];
            acc[nc] = __builtin_amdgcn_mfma_f32_16x16x32_bf16(ah[ks], bl, acc[nc], 0, 0, 0);
            acc[nc] = __builtin_amdgcn_mfma_f32_16x16x32_bf16(al[ks], bh, acc[nc], 0, 0, 0);
            acc[nc] = __builtin_amdgcn_mfma_f32_16x16x32_bf16(ah[ks], bh, acc[nc], 0, 0, 0);
        }
    }

    #pragma unroll
    for (int nc = 0; nc < 8; ++nc) {
        #pragma unroll
        for (int r = 0; r < 4; ++r)
            out[(size_t)(p0 + wv * 16 + quad * 4 + r) * HC + nc * 16 + lrow] = acc[nc][r];
    }
}

// ---------------------------------------------------------------------------
extern "C" void kernel_launch(void* const* d_in, const int* in_sizes, int n_in,
                              void* d_out, int out_size, void* d_ws, size_t ws_size,
                              hipStream_t stream)
{
    const float* z  = (const float*)d_in[0];
    const float* ls = (const float*)d_in[1];
    const float* lb = (const float*)d_in[2];
    const float* Wq = (const float*)d_in[3];
    const float* Wk = (const float*)d_in[4];
    const float* Wv = (const float*)d_in[5];
    const float* Wb = (const float*)d_in[6];
    const float* Wg = (const float*)d_in[7];
    const float* Wo = (const float*)d_in[8];

    float* ws = (float*)d_ws;
    const size_t BIG = (size_t)NPIX * HC;
    unsigned* q_pk  = (unsigned*)ws;
    unsigned* k_pk  = (unsigned*)(ws + BIG);
    unsigned* v_pk  = (unsigned*)(ws + 2 * BIG);
    float* g_ws     = ws + 3 * BIG;
    float* go_ws    = ws + 4 * BIG;
    float* bias_n   = ws + 5 * BIG;                            // NH*NPIX floats
    bf16x8* pk      = (bf16x8*)(bias_n + (size_t)NH * NPIX);   // 5 x 64 KB packs

    pack_w_kernel<<<40, 256, 0, stream>>>(Wq, Wk, Wv, Wg, Wo, pk);
    ln_proj_kernel<<<NPIX / 32, 256, 0, stream>>>(z, ls, lb, Wb, pk,
                                                  q_pk, k_pk, v_pk, g_ws, bias_n);
    attn_kernel<<<NN * NH, 256, 0, stream>>>(q_pk, k_pk, v_pk, g_ws, bias_n, go_ws);
    outproj_kernel<<<NPIX / 64, 256, 0, stream>>>(go_ws, pk, (float*)d_out);
}